// Round 2
// baseline (2034.536 us; speedup 1.0000x reference)
//
#include <hip/hip_runtime.h>
#include <math.h>

// Model: EGNN, N=6144 nodes, K=32 neighbors, 6 layers, D=128, M=64, HE=256.
// Key algebraic optimization: edge-MLP layer 1 factorizes:
//   hidden(i,j) = P[i] + Q[j] + rd_ij * w_r   (eb1 folded into P)
// with P = feats@ew1[0:128] + eb1, Q = feats@ew1[128:256].
// P and Q are produced by ONE fused GEMM into a [N,512] buffer (PQ).
// Neighbor selection (top_k over ranking) resolves to: {self} + (31 lowest-index
// adjacency entries) = all 32 dsts minus the max-index one; mask is all-true.

#define NN   6144
#define KNN  32
#define NL   6
#define DD   128
#define MM   64
#define HEE  256

__device__ __forceinline__ float silu_f(float x) {
    return x / (1.0f + expf(-x));
}

// ---------------- generic fp32 GEMM: C = [silu](A@B + bias) [+ Cresidual] ----
// 64x64 tile, 256 threads, 4x4 per thread, K-chunk 32. M,N multiples of 64.
// PQB mode: B is ew1[l] ([257,256] row-major); output column n<256 uses row-block
// 0:128 (fi weights), n>=256 uses row-block 128:256 (fj weights); bias only n<256.
template<bool SILU, bool RESID, bool PQB>
__global__ __launch_bounds__(256)
void gemm_kernel(const float* __restrict__ A, const float* __restrict__ B,
                 const float* __restrict__ bias, float* __restrict__ C,
                 int Mn, int Nn, int Kn)
{
    constexpr int BK = 32;
    __shared__ float lsA[64][BK + 1];   // +1 pad: conflict-free column reads
    __shared__ float lsB[BK][64];
    const int tid = threadIdx.x;
    const int tx = tid & 15, ty = tid >> 4;
    const int row0 = blockIdx.y * 64, col0 = blockIdx.x * 64;
    const int tx4 = tx * 4, ty4 = ty * 4;
    float acc[4][4] = {};

    for (int kk = 0; kk < Kn; kk += BK) {
#pragma unroll
        for (int i = 0; i < 8; ++i) {           // A: 64x32, coalesced
            int e = i * 256 + tid;
            int r = e >> 5, c = e & 31;
            int gk = kk + c;
            lsA[r][c] = (gk < Kn) ? A[(size_t)(row0 + r) * Kn + gk] : 0.0f;
        }
#pragma unroll
        for (int i = 0; i < 8; ++i) {           // B: 32x64, coalesced
            int e = i * 256 + tid;
            int r = e >> 6, c = e & 63;
            int gk = kk + r;
            float v = 0.0f;
            if (gk < Kn) {
                if (!PQB) {
                    v = B[(size_t)gk * Nn + col0 + c];
                } else {
                    int col = col0 + c;
                    v = (col < 256) ? B[(size_t)gk * 256 + col]
                                    : B[(size_t)(128 + gk) * 256 + (col - 256)];
                }
            }
            lsB[r][c] = v;
        }
        __syncthreads();
#pragma unroll 8
        for (int c = 0; c < BK; ++c) {
            float a0 = lsA[ty4 + 0][c], a1 = lsA[ty4 + 1][c];
            float a2 = lsA[ty4 + 2][c], a3 = lsA[ty4 + 3][c];
            float4 b = *(const float4*)(&lsB[c][tx4]);
            acc[0][0] += a0 * b.x; acc[0][1] += a0 * b.y; acc[0][2] += a0 * b.z; acc[0][3] += a0 * b.w;
            acc[1][0] += a1 * b.x; acc[1][1] += a1 * b.y; acc[1][2] += a1 * b.z; acc[1][3] += a1 * b.w;
            acc[2][0] += a2 * b.x; acc[2][1] += a2 * b.y; acc[2][2] += a2 * b.z; acc[2][3] += a2 * b.w;
            acc[3][0] += a3 * b.x; acc[3][1] += a3 * b.y; acc[3][2] += a3 * b.z; acc[3][3] += a3 * b.w;
        }
        __syncthreads();
    }
#pragma unroll
    for (int r = 0; r < 4; ++r) {
        int row = row0 + ty4 + r;
#pragma unroll
        for (int q = 0; q < 4; ++q) {
            int col = col0 + tx4 + q;
            float v = acc[r][q];
            if (bias && (!PQB || col < 256)) v += bias[col];
            if (SILU) v = silu_f(v);
            if (RESID) v += C[(size_t)row * Nn + col];
            C[(size_t)row * Nn + col] = v;
        }
    }
}

// ---------------- neighbor structure (exact top_k semantics) ----------------
__global__ __launch_bounds__(256)
void neighbor_kernel(const int* __restrict__ ei, const float* __restrict__ coords,
                     int* __restrict__ idx, float* __restrict__ rd)
{
    int i = blockIdx.x * blockDim.x + threadIdx.x;
    if (i >= NN) return;
    const int* dst = ei + (size_t)NN * KNN + (size_t)i * KNN;  // row 1 of edge_index
    int d[KNN];
    int maxd = -1;
#pragma unroll
    for (int k = 0; k < KNN; ++k) { d[k] = dst[k]; maxd = max(maxd, d[k]); }
    int sel[KNN];
    sel[0] = i;                      // self: ranking=-1, always picked first
    int pos = 1;
    bool dropped = false;
#pragma unroll
    for (int k = 0; k < KNN; ++k) {  // keep 31 lowest-index adj entries
        if (d[k] == maxd && !dropped) { dropped = true; continue; }
        if (pos < KNN) sel[pos++] = d[k];
    }
    float cx = coords[3 * i], cy = coords[3 * i + 1], cz = coords[3 * i + 2];
#pragma unroll
    for (int k = 0; k < KNN; ++k) {
        int j = sel[k];
        float dx = cx - coords[3 * j], dy = cy - coords[3 * j + 1], dz = cz - coords[3 * j + 2];
        rd[(size_t)i * KNN + k] = dx * dx + dy * dy + dz * dz;
        idx[(size_t)i * KNN + k] = j;
    }
}

// ---------------- fused edge kernel: one block per node ---------------------
// hidden[k][c] = silu(P[i][c] + Q[j_k][c] + rd_k*wr[c]); m_i = sum_k silu(hidden@W2+eb2)
// writes h[i] = [feats[i] (128), m_i (64)].  PQ layout: row i = [P_i(256), Q_i(256)].
__global__ __launch_bounds__(256)
void edge_kernel(const float* __restrict__ PQ,
                 const float* __restrict__ wr, const float* __restrict__ W2,
                 const float* __restrict__ eb2, const int* __restrict__ idx,
                 const float* __restrict__ rd, const float* __restrict__ feats,
                 float* __restrict__ h)
{
    __shared__ float lsH[KNN][260];    // stride 260 -> rows spread across banks
    __shared__ float lsW[64][64];      // W2 chunk (64 c-rows)
    __shared__ float lsP[HEE];
    __shared__ float lsWr[HEE];
    __shared__ float lsM[KNN][MM];
    __shared__ int   lsIdx[KNN];
    __shared__ float lsRd[KNN];

    const int i = blockIdx.x;
    const int t = threadIdx.x;

    lsP[t]  = PQ[(size_t)i * 512 + t];                 // P half
    lsWr[t] = wr[t];
    if (t < KNN) { lsIdx[t] = idx[(size_t)i * KNN + t]; lsRd[t] = rd[(size_t)i * KNN + t]; }
    __syncthreads();

#pragma unroll 4
    for (int k = 0; k < KNN; ++k) {
        int j = lsIdx[k];
        float rdk = lsRd[k];
        float q = PQ[(size_t)j * 512 + 256 + t];       // gathered Q row, coalesced
        lsH[k][t] = silu_f(lsP[t] + q + rdk * lsWr[t]);
    }

    const int kr = t >> 3;            // 0..31 : which edge row
    const int o0 = (t & 7) * 8;       // 8 outputs per thread
    float acc[8] = {};
    for (int cc = 0; cc < 4; ++cc) {
        __syncthreads();              // lsH ready (cc=0) / lsW readers done (cc>0)
#pragma unroll
        for (int it = 0; it < 16; ++it) {
            int e = it * 256 + t;
            lsW[e >> 6][e & 63] = W2[cc * 4096 + e];
        }
        __syncthreads();
#pragma unroll 4
        for (int c = 0; c < 64; ++c) {
            float hv = lsH[kr][cc * 64 + c];
            float4 w0 = *(const float4*)(&lsW[c][o0]);
            float4 w1 = *(const float4*)(&lsW[c][o0 + 4]);
            acc[0] += hv * w0.x; acc[1] += hv * w0.y; acc[2] += hv * w0.z; acc[3] += hv * w0.w;
            acc[4] += hv * w1.x; acc[5] += hv * w1.y; acc[6] += hv * w1.z; acc[7] += hv * w1.w;
        }
    }
#pragma unroll
    for (int q = 0; q < 8; ++q)
        lsM[kr][o0 + q] = silu_f(acc[q] + eb2[o0 + q]);
    __syncthreads();

    if (t < MM) {                      // m_i = sum over 32 edges
        float s = 0.0f;
        for (int k = 0; k < KNN; ++k) s += lsM[k][t];
        h[(size_t)i * 192 + DD + t] = s;
    } else if (t >= 128 && t < 256) {  // copy feats into h[:,0:128]
        h[(size_t)i * 192 + (t - 128)] = feats[(size_t)i * DD + (t - 128)];
    }
}

// ---------------- deterministic column sum (stage 1) ------------------------
__global__ __launch_bounds__(256)
void colsum_kernel(const float* __restrict__ F, float* __restrict__ partial)
{
    __shared__ float ls[2][DD];
    const int b = blockIdx.x;          // 96 blocks x 64 rows
    const int t = threadIdx.x;
    const int c = t & 127, rg = t >> 7;
    float s = 0.0f;
    const int r0 = b * 64;
    for (int r = rg; r < 64; r += 2) s += F[(size_t)(r0 + r) * DD + c];
    ls[rg][c] = s;
    __syncthreads();
    if (t < DD) partial[(size_t)b * DD + t] = ls[0][t] + ls[1][t];
}

// ---------------- graph decoder + normalize (single block) ------------------
__global__ __launch_bounds__(128)
void final_kernel(const float* __restrict__ partial, const float* __restrict__ gw1,
                  const float* __restrict__ gb1, const float* __restrict__ gw2,
                  const float* __restrict__ gb2, float* __restrict__ out)
{
    __shared__ float lg[DD], lu[DD], red[DD];
    const int t = threadIdx.x;
    float s = 0.0f;
    for (int b = 0; b < 96; ++b) s += partial[(size_t)b * DD + t];
    lg[t] = s;
    __syncthreads();
    float a = 0.0f;
    for (int c = 0; c < DD; ++c) a += lg[c] * gw1[(size_t)c * DD + t];
    lu[t] = silu_f(a + gb1[t]);
    __syncthreads();
    float v = 0.0f;
    for (int c = 0; c < DD; ++c) v += lu[c] * gw2[(size_t)c * DD + t];
    v += gb2[t];
    red[t] = v * v;
    __syncthreads();
    for (int sft = 64; sft > 0; sft >>= 1) {
        if (t < sft) red[t] += red[t + sft];
        __syncthreads();
    }
    float nrm = sqrtf(red[0]);
    out[t] = v / fmaxf(nrm, 1e-12f);
}

// ---------------------------------------------------------------------------
extern "C" void kernel_launch(void* const* d_in, const int* in_sizes, int n_in,
                              void* d_out, int out_size, void* d_ws, size_t ws_size,
                              hipStream_t stream)
{
    const float* x      = (const float*)d_in[0];
    const float* coords = (const float*)d_in[1];
    const int*   ei     = (const int*)d_in[2];
    const float* w_enc  = (const float*)d_in[3];
    const float* b_enc  = (const float*)d_in[4];
    const float* ew1    = (const float*)d_in[5];
    const float* eb1    = (const float*)d_in[6];
    const float* ew2    = (const float*)d_in[7];
    const float* eb2    = (const float*)d_in[8];
    const float* nw1    = (const float*)d_in[9];
    const float* nb1    = (const float*)d_in[10];
    const float* nw2    = (const float*)d_in[11];
    const float* nb2    = (const float*)d_in[12];
    const float* dw1    = (const float*)d_in[13];
    const float* db1    = (const float*)d_in[14];
    const float* dw2    = (const float*)d_in[15];
    const float* db2    = (const float*)d_in[16];
    const float* gw1    = (const float*)d_in[17];
    const float* gb1    = (const float*)d_in[18];
    const float* gw2    = (const float*)d_in[19];
    const float* gb2    = (const float*)d_in[20];
    float* out = (float*)d_out;

    // workspace layout (floats): ~22 MB total
    float* ws      = (float*)d_ws;
    float* feats   = ws;                         // 6144*128
    float* PQ      = feats + 786432;             // 6144*512 ([P|Q] per row; reused as T)
    float* hbuf    = PQ + 3145728;               // 6144*192
    int*   idxbuf  = (int*)(hbuf + 1179648);     // 6144*32 int
    float* rdbuf   = (float*)(idxbuf + 196608);  // 6144*32
    float* partial = rdbuf + 196608;             // 96*128

    float* Tbuf = PQ;                  // [6144,256] node-MLP hidden, after PQ consumed
    float* Ubuf = PQ;                  // [6144,128] node-dec hidden
    float* Fbuf = PQ + 786432;         // [6144,128] node-dec output

    dim3 blk(256);

    // encoder: feats = x @ w_enc + b_enc
    gemm_kernel<false, false, false><<<dim3(2, 96), blk, 0, stream>>>(x, w_enc, b_enc, feats, NN, DD, 68);
    neighbor_kernel<<<24, blk, 0, stream>>>(ei, coords, idxbuf, rdbuf);

    for (int l = 0; l < NL; ++l) {
        const float* W1 = ew1 + (size_t)l * 257 * 256;
        // PQ = feats @ [ew1_fi | ew1_fj] (+ eb1 on P half)
        gemm_kernel<false, false, true><<<dim3(8, 96), blk, 0, stream>>>(feats, W1, eb1 + l * 256, PQ, NN, 512, DD);
        // per-node edge MLP second layer + aggregate; h = [feats, m]
        edge_kernel<<<NN, blk, 0, stream>>>(PQ, W1 + 256 * 256,
                                            ew2 + (size_t)l * 256 * 64, eb2 + l * 64,
                                            idxbuf, rdbuf, feats, hbuf);
        // T = silu(h @ nw1 + nb1) ; feats = T @ nw2 + nb2 + feats
        gemm_kernel<true, false, false><<<dim3(4, 96), blk, 0, stream>>>(hbuf, nw1 + (size_t)l * 192 * 256, nb1 + l * 256, Tbuf, NN, HEE, 192);
        gemm_kernel<false, true, false><<<dim3(2, 96), blk, 0, stream>>>(Tbuf, nw2 + (size_t)l * 256 * 128, nb2 + l * 128, feats, NN, DD, HEE);
    }

    // node decoder
    gemm_kernel<true, false, false><<<dim3(2, 96), blk, 0, stream>>>(feats, dw1, db1, Ubuf, NN, DD, DD);
    gemm_kernel<false, false, false><<<dim3(2, 96), blk, 0, stream>>>(Ubuf, dw2, db2, Fbuf, NN, DD, DD);
    // graph sum (deterministic 2-stage) + graph decoder + normalize
    colsum_kernel<<<96, blk, 0, stream>>>(Fbuf, partial);
    final_kernel<<<1, dim3(128), 0, stream>>>(partial, gw1, gb1, gw2, gb2, out);
}

// Round 3
// 1159.791 us; speedup vs baseline: 1.7542x; 1.7542x over previous
//
#include <hip/hip_runtime.h>
#include <hip/hip_bf16.h>
#include <math.h>

// EGNN, N=6144, K=32, L=6, D=128, M=64, HE=256.
// Edge-MLP layer 1 factorizes: hidden(i,j) = silu(P[i] + Q[j] + rd_ij*wr), with
// P = feats@ew1[0:128] + eb1, Q = feats@ew1[128:256], produced by ONE GEMM -> PQ [N,512].
// Edge-MLP layer 2 ([32,256]@[256,64] per node) runs on bf16 MFMA (16x16x32),
// with ew2 pre-packed into B-fragment order (one 16B load per lane per frag).
// Neighbor selection (top_k over ranking) = {self} + 31 lowest-index adj entries.

#define NN   6144
#define KNN  32
#define NL   6
#define DD   128
#define MM   64
#define HEE  256

typedef short bf16x8 __attribute__((ext_vector_type(8)));
typedef float f32x4  __attribute__((ext_vector_type(4)));

__device__ __forceinline__ float silu_f(float x) {
    return x / (1.0f + expf(-x));
}
__device__ __forceinline__ float silu_fast(float x) {
    return __fdividef(x, 1.0f + __expf(-x));
}
__device__ __forceinline__ unsigned short f2bf(float x) {
    __hip_bfloat16 b = __float2bfloat16(x);
    return *reinterpret_cast<unsigned short*>(&b);
}

// ---------------- generic fp32 GEMM: C = [silu](A@B + bias) [+ Cresidual] ----
// 64x64 tile, 256 threads, 4x4 per thread, K-chunk 32. M,N multiples of 64.
// PQB mode: B is ew1[l] ([257,256] row-major); output col n<256 uses rows 0:128
// (fi weights), n>=256 uses rows 128:256 (fj weights); bias only n<256.
template<bool SILU, bool RESID, bool PQB>
__global__ __launch_bounds__(256)
void gemm_kernel(const float* __restrict__ A, const float* __restrict__ B,
                 const float* __restrict__ bias, float* __restrict__ C,
                 int Mn, int Nn, int Kn)
{
    constexpr int BK = 32;
    __shared__ float lsA[64][BK + 1];
    __shared__ float lsB[BK][64];
    const int tid = threadIdx.x;
    const int tx = tid & 15, ty = tid >> 4;
    const int row0 = blockIdx.y * 64, col0 = blockIdx.x * 64;
    const int tx4 = tx * 4, ty4 = ty * 4;
    float acc[4][4] = {};

    for (int kk = 0; kk < Kn; kk += BK) {
#pragma unroll
        for (int i = 0; i < 8; ++i) {           // A: 64x32, coalesced
            int e = i * 256 + tid;
            int r = e >> 5, c = e & 31;
            int gk = kk + c;
            lsA[r][c] = (gk < Kn) ? A[(size_t)(row0 + r) * Kn + gk] : 0.0f;
        }
#pragma unroll
        for (int i = 0; i < 8; ++i) {           // B: 32x64, coalesced
            int e = i * 256 + tid;
            int r = e >> 6, c = e & 63;
            int gk = kk + r;
            float v = 0.0f;
            if (gk < Kn) {
                if (!PQB) {
                    v = B[(size_t)gk * Nn + col0 + c];
                } else {
                    int col = col0 + c;
                    v = (col < 256) ? B[(size_t)gk * 256 + col]
                                    : B[(size_t)(128 + gk) * 256 + (col - 256)];
                }
            }
            lsB[r][c] = v;
        }
        __syncthreads();
#pragma unroll 8
        for (int c = 0; c < BK; ++c) {
            float a0 = lsA[ty4 + 0][c], a1 = lsA[ty4 + 1][c];
            float a2 = lsA[ty4 + 2][c], a3 = lsA[ty4 + 3][c];
            float4 b = *(const float4*)(&lsB[c][tx4]);
            acc[0][0] += a0 * b.x; acc[0][1] += a0 * b.y; acc[0][2] += a0 * b.z; acc[0][3] += a0 * b.w;
            acc[1][0] += a1 * b.x; acc[1][1] += a1 * b.y; acc[1][2] += a1 * b.z; acc[1][3] += a1 * b.w;
            acc[2][0] += a2 * b.x; acc[2][1] += a2 * b.y; acc[2][2] += a2 * b.z; acc[2][3] += a2 * b.w;
            acc[3][0] += a3 * b.x; acc[3][1] += a3 * b.y; acc[3][2] += a3 * b.z; acc[3][3] += a3 * b.w;
        }
        __syncthreads();
    }
#pragma unroll
    for (int r = 0; r < 4; ++r) {
        int row = row0 + ty4 + r;
#pragma unroll
        for (int q = 0; q < 4; ++q) {
            int col = col0 + tx4 + q;
            float v = acc[r][q];
            if (bias && (!PQB || col < 256)) v += bias[col];
            if (SILU) v = silu_f(v);
            if (RESID) v += C[(size_t)row * Nn + col];
            C[(size_t)row * Nn + col] = v;
        }
    }
}

// ---------------- neighbor structure (exact top_k semantics) ----------------
__global__ __launch_bounds__(256)
void neighbor_kernel(const int* __restrict__ ei, const float* __restrict__ coords,
                     int* __restrict__ idx, float* __restrict__ rd)
{
    int i = blockIdx.x * blockDim.x + threadIdx.x;
    if (i >= NN) return;
    const int* dst = ei + (size_t)NN * KNN + (size_t)i * KNN;  // row 1 of edge_index
    int d[KNN];
    int maxd = -1;
#pragma unroll
    for (int k = 0; k < KNN; ++k) { d[k] = dst[k]; maxd = max(maxd, d[k]); }
    int sel[KNN];
    sel[0] = i;                      // self: ranking=-1, always picked first
    int pos = 1;
    bool dropped = false;
#pragma unroll
    for (int k = 0; k < KNN; ++k) {  // keep 31 lowest-index adj entries
        if (d[k] == maxd && !dropped) { dropped = true; continue; }
        if (pos < KNN) sel[pos++] = d[k];
    }
    float cx = coords[3 * i], cy = coords[3 * i + 1], cz = coords[3 * i + 2];
#pragma unroll
    for (int k = 0; k < KNN; ++k) {
        int j = sel[k];
        float dx = cx - coords[3 * j], dy = cy - coords[3 * j + 1], dz = cz - coords[3 * j + 2];
        rd[(size_t)i * KNN + k] = dx * dx + dy * dy + dz * dz;
        idx[(size_t)i * KNN + k] = j;
    }
}

// ---------------- pack ew2 (6 layers [256][64]) into MFMA B-frag bf16 -------
// w2p[((l*4+ct)*8+ks)*512 + lane*8 + j] = bf16(ew2[l][ks*32+(lane>>4)*8+j][ct*16+(lane&15)])
__global__ __launch_bounds__(256)
void pack_w2_kernel(const float* __restrict__ ew2, unsigned short* __restrict__ w2p)
{
    int id = blockIdx.x * 256 + threadIdx.x;   // exactly 6*4*8*64 = 12288 threads
    int lane = id & 63, ks = (id >> 6) & 7, ct = (id >> 9) & 3, l = id >> 11;
    const float* W = ew2 + (size_t)l * 256 * 64;
    int k0 = ks * 32 + (lane >> 4) * 8, c = ct * 16 + (lane & 15);
    unsigned short* o = w2p + (size_t)id * 8;
#pragma unroll
    for (int j = 0; j < 8; ++j) o[j] = f2bf(W[(size_t)(k0 + j) * 64 + c]);
}

// ---------------- fused edge kernel: one block per node, MFMA matvec --------
// hidden[k][c] = silu(P[i][c] + Q[j_k][c] + rd_k*wr[c])  (bf16 in LDS)
// m_i = sum_k silu(hidden @ W2 + eb2);  h[i] = [feats[i] (128), m_i (64)]
__global__ __launch_bounds__(256)
void edge_kernel(const float* __restrict__ PQ, const float* __restrict__ wr,
                 const unsigned short* __restrict__ w2p, const float* __restrict__ eb2,
                 const int* __restrict__ idx, const float* __restrict__ rd,
                 const float* __restrict__ feats, float* __restrict__ h)
{
    __shared__ unsigned short lsH[32 * 264];   // bf16, row stride 528B: banks spread
    __shared__ float lsPart[2][4][16];
    __shared__ int   lsIdx[KNN];
    __shared__ float lsRd[KNN];

    const int i = blockIdx.x;
    const int t = threadIdx.x;

    if (t < KNN) { lsIdx[t] = idx[(size_t)i * KNN + t]; lsRd[t] = rd[(size_t)i * KNN + t]; }
    __syncthreads();

    // hidden build: thread handles cols (cp,cp+1), rows hh*16..hh*16+15
    {
        const int cp = (t & 127) * 2;
        const int hh = t >> 7;
        float2 p2 = *(const float2*)&PQ[(size_t)i * 512 + cp];
        float2 wv = *(const float2*)&wr[cp];
#pragma unroll
        for (int k = 0; k < 16; ++k) {
            int kk = hh * 16 + k;
            int j = lsIdx[kk];
            float rdk = lsRd[kk];
            float2 q = *(const float2*)&PQ[(size_t)j * 512 + 256 + cp];
            float a0 = p2.x + q.x + rdk * wv.x;
            float a1 = p2.y + q.y + rdk * wv.y;
            a0 = silu_fast(a0);
            a1 = silu_fast(a1);
            unsigned pk = ((unsigned)f2bf(a1) << 16) | (unsigned)f2bf(a0);
            *(unsigned*)&lsH[kk * 264 + cp] = pk;
        }
    }
    __syncthreads();

    // MFMA: [32,256] @ [256,64]; 8 tiles (2 row x 4 col) over 4 waves
    const int w = t >> 6, l = t & 63;
    const int rt = w & 1, cb = (w >> 1) * 2;
    const int lr = l & 15, lg = l >> 4;
    const int arow = rt * 16 + lr;
    f32x4 acc0 = {0.f, 0.f, 0.f, 0.f}, acc1 = {0.f, 0.f, 0.f, 0.f};
#pragma unroll
    for (int ks = 0; ks < 8; ++ks) {
        bf16x8 a  = *(const bf16x8*)&lsH[arow * 264 + ks * 32 + lg * 8];
        bf16x8 b0 = *(const bf16x8*)&w2p[(size_t)(cb * 8 + ks) * 512 + l * 8];
        bf16x8 b1 = *(const bf16x8*)&w2p[(size_t)((cb + 1) * 8 + ks) * 512 + l * 8];
        acc0 = __builtin_amdgcn_mfma_f32_16x16x32_bf16(a, b0, acc0, 0, 0, 0);
        acc1 = __builtin_amdgcn_mfma_f32_16x16x32_bf16(a, b1, acc1, 0, 0, 0);
    }
    // epilogue: m_ij = silu(acc + eb2); sum over the 16 rows of this row-tile
    float e0 = eb2[cb * 16 + lr], e1 = eb2[(cb + 1) * 16 + lr];
    float s0 = 0.f, s1 = 0.f;
#pragma unroll
    for (int r = 0; r < 4; ++r) {
        float v0 = acc0[r] + e0; s0 += silu_fast(v0);
        float v1 = acc1[r] + e1; s1 += silu_fast(v1);
    }
    s0 += __shfl_xor(s0, 16); s0 += __shfl_xor(s0, 32);
    s1 += __shfl_xor(s1, 16); s1 += __shfl_xor(s1, 32);
    if (lg == 0) { lsPart[rt][cb][lr] = s0; lsPart[rt][cb + 1][lr] = s1; }
    __syncthreads();

    if (t < MM) {                       // m_i = rowtile0 + rowtile1
        float m = lsPart[0][t >> 4][t & 15] + lsPart[1][t >> 4][t & 15];
        h[(size_t)i * 192 + DD + t] = m;
    } else if (t < 192) {               // h[:,0:128] = feats
        h[(size_t)i * 192 + (t - 64)] = feats[(size_t)i * DD + (t - 64)];
    }
}

// ---------------- deterministic column sum (stage 1) ------------------------
__global__ __launch_bounds__(256)
void colsum_kernel(const float* __restrict__ F, float* __restrict__ partial)
{
    __shared__ float ls[2][DD];
    const int b = blockIdx.x;          // 96 blocks x 64 rows
    const int t = threadIdx.x;
    const int c = t & 127, rg = t >> 7;
    float s = 0.0f;
    const int r0 = b * 64;
    for (int r = rg; r < 64; r += 2) s += F[(size_t)(r0 + r) * DD + c];
    ls[rg][c] = s;
    __syncthreads();
    if (t < DD) partial[(size_t)b * DD + t] = ls[0][t] + ls[1][t];
}

// ---------------- graph decoder + normalize (single block) ------------------
__global__ __launch_bounds__(128)
void final_kernel(const float* __restrict__ partial, const float* __restrict__ gw1,
                  const float* __restrict__ gb1, const float* __restrict__ gw2,
                  const float* __restrict__ gb2, float* __restrict__ out)
{
    __shared__ float lg[DD], lu[DD], red[DD];
    const int t = threadIdx.x;
    float s = 0.0f;
    for (int b = 0; b < 96; ++b) s += partial[(size_t)b * DD + t];
    lg[t] = s;
    __syncthreads();
    float a = 0.0f;
    for (int c = 0; c < DD; ++c) a += lg[c] * gw1[(size_t)c * DD + t];
    lu[t] = silu_f(a + gb1[t]);
    __syncthreads();
    float v = 0.0f;
    for (int c = 0; c < DD; ++c) v += lu[c] * gw2[(size_t)c * DD + t];
    v += gb2[t];
    red[t] = v * v;
    __syncthreads();
    for (int sft = 64; sft > 0; sft >>= 1) {
        if (t < sft) red[t] += red[t + sft];
        __syncthreads();
    }
    float nrm = sqrtf(red[0]);
    out[t] = v / fmaxf(nrm, 1e-12f);
}

// ---------------------------------------------------------------------------
extern "C" void kernel_launch(void* const* d_in, const int* in_sizes, int n_in,
                              void* d_out, int out_size, void* d_ws, size_t ws_size,
                              hipStream_t stream)
{
    const float* x      = (const float*)d_in[0];
    const float* coords = (const float*)d_in[1];
    const int*   ei     = (const int*)d_in[2];
    const float* w_enc  = (const float*)d_in[3];
    const float* b_enc  = (const float*)d_in[4];
    const float* ew1    = (const float*)d_in[5];
    const float* eb1    = (const float*)d_in[6];
    const float* ew2    = (const float*)d_in[7];
    const float* eb2    = (const float*)d_in[8];
    const float* nw1    = (const float*)d_in[9];
    const float* nb1    = (const float*)d_in[10];
    const float* nw2    = (const float*)d_in[11];
    const float* nb2    = (const float*)d_in[12];
    const float* dw1    = (const float*)d_in[13];
    const float* db1    = (const float*)d_in[14];
    const float* dw2    = (const float*)d_in[15];
    const float* db2    = (const float*)d_in[16];
    const float* gw1    = (const float*)d_in[17];
    const float* gb1    = (const float*)d_in[18];
    const float* gw2    = (const float*)d_in[19];
    const float* gb2    = (const float*)d_in[20];
    float* out = (float*)d_out;

    // workspace layout (floats)
    float* ws      = (float*)d_ws;
    float* feats   = ws;                         // 6144*128
    float* PQ      = feats + 786432;             // 6144*512 ([P|Q] per row; reused as T)
    float* hbuf    = PQ + 3145728;               // 6144*192
    int*   idxbuf  = (int*)(hbuf + 1179648);     // 6144*32 int
    float* rdbuf   = (float*)(idxbuf + 196608);  // 6144*32
    float* partial = rdbuf + 196608;             // 96*128
    unsigned short* w2p = (unsigned short*)(partial + 12288);  // 6*16384 bf16

    float* Tbuf = PQ;                  // [6144,256] node-MLP hidden (PQ consumed)
    float* Ubuf = PQ;                  // [6144,128] node-dec hidden
    float* Fbuf = PQ + 786432;         // [6144,128] node-dec output

    dim3 blk(256);

    // encoder + neighbor structure + ew2 pre-pack
    gemm_kernel<false, false, false><<<dim3(2, 96), blk, 0, stream>>>(x, w_enc, b_enc, feats, NN, DD, 68);
    neighbor_kernel<<<24, blk, 0, stream>>>(ei, coords, idxbuf, rdbuf);
    pack_w2_kernel<<<48, blk, 0, stream>>>(ew2, w2p);

    for (int l = 0; l < NL; ++l) {
        const float* W1 = ew1 + (size_t)l * 257 * 256;
        // PQ = feats @ [ew1_fi | ew1_fj] (+ eb1 on P half)
        gemm_kernel<false, false, true><<<dim3(8, 96), blk, 0, stream>>>(feats, W1, eb1 + l * 256, PQ, NN, 512, DD);
        // per-node edge MLP second layer (bf16 MFMA) + aggregate; h = [feats, m]
        edge_kernel<<<NN, blk, 0, stream>>>(PQ, W1 + 256 * 256, w2p + (size_t)l * 16384,
                                            eb2 + l * 64, idxbuf, rdbuf, feats, hbuf);
        // T = silu(h @ nw1 + nb1) ; feats = T @ nw2 + nb2 + feats
        gemm_kernel<true, false, false><<<dim3(4, 96), blk, 0, stream>>>(hbuf, nw1 + (size_t)l * 192 * 256, nb1 + l * 256, Tbuf, NN, HEE, 192);
        gemm_kernel<false, true, false><<<dim3(2, 96), blk, 0, stream>>>(Tbuf, nw2 + (size_t)l * 256 * 128, nb2 + l * 128, feats, NN, DD, HEE);
    }

    // node decoder
    gemm_kernel<true, false, false><<<dim3(2, 96), blk, 0, stream>>>(feats, dw1, db1, Ubuf, NN, DD, DD);
    gemm_kernel<false, false, false><<<dim3(2, 96), blk, 0, stream>>>(Ubuf, dw2, db2, Fbuf, NN, DD, DD);
    // graph sum (deterministic 2-stage) + graph decoder + normalize
    colsum_kernel<<<96, blk, 0, stream>>>(Fbuf, partial);
    final_kernel<<<1, dim3(128), 0, stream>>>(partial, gw1, gb1, gw2, gb2, out);
}

// Round 4
// 566.257 us; speedup vs baseline: 3.5930x; 2.0482x over previous
//
#include <hip/hip_runtime.h>
#include <hip/hip_bf16.h>
#include <math.h>

// EGNN, N=6144, K=32, L=6, D=128, M=64, HE=256.
// Edge-MLP layer 1 factorizes: hidden(i,j) = silu(P[i] + Q[j] + rd_ij*wr), with
// PQ = feats @ [ew1_fi | ew1_fj] (+eb1 on P half) -> [N,512], one bf16-MFMA GEMM.
// Edge-MLP layer 2 ([32,256]@[256,64] per node) on bf16 MFMA with pre-packed ew2.
// ALL layer GEMMs (PQ, nodeMLP1, nodeMLP2, node-dec) are bf16-MFMA: A staged
// fp32->bf16 in LDS (full K, stride K+8 => row stride 16 mod 128 B, 2-way free),
// B pre-packed to fragment order (one 16B coalesced load/lane, L2-resident).
// Neighbor selection (top_k over ranking) = {self} + 31 lowest-index adj entries.

#define NN   6144
#define KNN  32
#define NL   6
#define DD   128
#define MM   64
#define HEE  256

typedef short bf16x8 __attribute__((ext_vector_type(8)));
typedef float f32x4  __attribute__((ext_vector_type(4)));

__device__ __forceinline__ float silu_f(float x) {
    return x / (1.0f + expf(-x));
}
__device__ __forceinline__ float silu_fast(float x) {
    return __fdividef(x, 1.0f + __expf(-x));
}
__device__ __forceinline__ unsigned short f2bf(float x) {
    __hip_bfloat16 b = __float2bfloat16(x);
    return *reinterpret_cast<unsigned short*>(&b);
}

// ---------------- fp32 GEMM (encoder only: K=68) ----------------------------
__global__ __launch_bounds__(256)
void gemm_kernel(const float* __restrict__ A, const float* __restrict__ B,
                 const float* __restrict__ bias, float* __restrict__ C,
                 int Mn, int Nn, int Kn)
{
    constexpr int BK = 32;
    __shared__ float lsA[64][BK + 1];
    __shared__ float lsB[BK][64];
    const int tid = threadIdx.x;
    const int tx = tid & 15, ty = tid >> 4;
    const int row0 = blockIdx.y * 64, col0 = blockIdx.x * 64;
    const int tx4 = tx * 4, ty4 = ty * 4;
    float acc[4][4] = {};

    for (int kk = 0; kk < Kn; kk += BK) {
#pragma unroll
        for (int i = 0; i < 8; ++i) {
            int e = i * 256 + tid;
            int r = e >> 5, c = e & 31;
            int gk = kk + c;
            lsA[r][c] = (gk < Kn) ? A[(size_t)(row0 + r) * Kn + gk] : 0.0f;
        }
#pragma unroll
        for (int i = 0; i < 8; ++i) {
            int e = i * 256 + tid;
            int r = e >> 6, c = e & 63;
            int gk = kk + r;
            lsB[r][c] = (gk < Kn) ? B[(size_t)gk * Nn + col0 + c] : 0.0f;
        }
        __syncthreads();
#pragma unroll 8
        for (int c = 0; c < BK; ++c) {
            float a0 = lsA[ty4 + 0][c], a1 = lsA[ty4 + 1][c];
            float a2 = lsA[ty4 + 2][c], a3 = lsA[ty4 + 3][c];
            float4 b = *(const float4*)(&lsB[c][tx4]);
            acc[0][0] += a0 * b.x; acc[0][1] += a0 * b.y; acc[0][2] += a0 * b.z; acc[0][3] += a0 * b.w;
            acc[1][0] += a1 * b.x; acc[1][1] += a1 * b.y; acc[1][2] += a1 * b.z; acc[1][3] += a1 * b.w;
            acc[2][0] += a2 * b.x; acc[2][1] += a2 * b.y; acc[2][2] += a2 * b.z; acc[2][3] += a2 * b.w;
            acc[3][0] += a3 * b.x; acc[3][1] += a3 * b.y; acc[3][2] += a3 * b.z; acc[3][3] += a3 * b.w;
        }
        __syncthreads();
    }
#pragma unroll
    for (int r = 0; r < 4; ++r) {
        int row = row0 + ty4 + r;
#pragma unroll
        for (int q = 0; q < 4; ++q) {
            int col = col0 + tx4 + q;
            float v = acc[r][q] + bias[col];
            C[(size_t)row * Nn + col] = v;
        }
    }
}

// ---------------- bf16 MFMA GEMM: C = [silu](A@Bp + bias) [+ C] -------------
// 64x64 tile, 4 waves (2x2), full-K A staging fp32->bf16 in LDS.
// Bp is pre-packed fragment order: Bp[((ct*NKS+ks)*64+lane)*8+j]
//   = bf16(B[ks*32+(lane>>4)*8+j][ct*16+(lane&15)])
template<int KN, bool SILU, bool RESID, bool PQB>
__global__ __launch_bounds__(256)
void mfma_gemm(const float* __restrict__ A, const unsigned short* __restrict__ Bp,
               const float* __restrict__ bias, float* __restrict__ C, int Nn)
{
    constexpr int NKS = KN / 32;
    constexpr int LDA = KN + 8;          // row stride: 2*KN+16 bytes == 16 mod 128
    __shared__ unsigned short lsA[64 * LDA];
    const int t = threadIdx.x;
    const int row0 = blockIdx.y * 64, col0 = blockIdx.x * 64;

#pragma unroll
    for (int e0 = 0; e0 < 64 * KN; e0 += 1024) {
        int e = e0 + t * 4;
        int r = e / KN, c = e % KN;      // KN constexpr -> cheap
        float4 v = *(const float4*)&A[(size_t)(row0 + r) * KN + c];
        unsigned u0 = ((unsigned)f2bf(v.y) << 16) | f2bf(v.x);
        unsigned u1 = ((unsigned)f2bf(v.w) << 16) | f2bf(v.z);
        *(uint2*)&lsA[r * LDA + c] = make_uint2(u0, u1);
    }
    __syncthreads();

    const int w = t >> 6, l = t & 63;
    const int wr = w & 1, wc = w >> 1;   // wave grid 2x2
    const int lr = l & 15, lg = l >> 4;
    const int ct0 = blockIdx.x * 4 + wc * 2;           // global col-tile
    const int aoff = (wr * 32 + lr) * LDA + lg * 8;
    f32x4 acc[2][2] = {};
#pragma unroll
    for (int ks = 0; ks < NKS; ++ks) {
        bf16x8 a0 = *(const bf16x8*)&lsA[aoff + ks * 32];
        bf16x8 a1 = *(const bf16x8*)&lsA[aoff + 16 * LDA + ks * 32];
        bf16x8 b0 = *(const bf16x8*)&Bp[((size_t)(ct0 * NKS + ks) * 64 + l) * 8];
        bf16x8 b1 = *(const bf16x8*)&Bp[((size_t)((ct0 + 1) * NKS + ks) * 64 + l) * 8];
        acc[0][0] = __builtin_amdgcn_mfma_f32_16x16x32_bf16(a0, b0, acc[0][0], 0, 0, 0);
        acc[0][1] = __builtin_amdgcn_mfma_f32_16x16x32_bf16(a0, b1, acc[0][1], 0, 0, 0);
        acc[1][0] = __builtin_amdgcn_mfma_f32_16x16x32_bf16(a1, b0, acc[1][0], 0, 0, 0);
        acc[1][1] = __builtin_amdgcn_mfma_f32_16x16x32_bf16(a1, b1, acc[1][1], 0, 0, 0);
    }
#pragma unroll
    for (int rt = 0; rt < 2; ++rt) {
#pragma unroll
        for (int ctl = 0; ctl < 2; ++ctl) {
            int col = col0 + wc * 32 + ctl * 16 + lr;
            float bv = (!PQB || col < 256) ? bias[col] : 0.0f;
#pragma unroll
            for (int r = 0; r < 4; ++r) {
                int row = row0 + wr * 32 + rt * 16 + lg * 4 + r;
                float v = acc[rt][ctl][r] + bv;
                if (SILU) v = silu_f(v);
                size_t off = (size_t)row * Nn + col;
                if (RESID) v += C[off];
                C[off] = v;
            }
        }
    }
}

// ---------------- unified weight pre-pack (all layers, all matrices) --------
// 1984 units of (ct,ks); unit -> 64 lanes x 8 bf16. Layout matches mfma_gemm/edge.
__global__ __launch_bounds__(256)
void pack_all(const float* __restrict__ ew1, const float* __restrict__ ew2,
              const float* __restrict__ nw1, const float* __restrict__ nw2,
              const float* __restrict__ dw1, const float* __restrict__ dw2,
              unsigned short* __restrict__ Bpq, unsigned short* __restrict__ Bn1,
              unsigned short* __restrict__ Bn2, unsigned short* __restrict__ w2p,
              unsigned short* __restrict__ Bd1, unsigned short* __restrict__ Bd2)
{
    const int t = threadIdx.x;
    const int u = blockIdx.x * 4 + (t >> 6);
    const int lane = t & 63;
    const float* src; unsigned short* dst;
    int nks, nc, ctd, ctc, ks;
    if (u < 1920) {
        int l = u / 320, r = u % 320;
        if (r < 128) {                    // PQ: ew1 split-source, 32 ct x 4 ks
            ctd = r >> 2; ks = r & 3; nks = 4; nc = 256; ctc = ctd & 15;
            src = ew1 + (size_t)l * 257 * 256 + (ctd >= 16 ? 128 * 256 : 0);
            dst = Bpq + (size_t)l * 65536;
        } else if (r < 224) {             // n1: [192][256], 16 ct x 6 ks
            int rr = r - 128; ctd = rr / 6; ks = rr % 6; nks = 6; nc = 256; ctc = ctd;
            src = nw1 + (size_t)l * 192 * 256; dst = Bn1 + (size_t)l * 49152;
        } else if (r < 288) {             // n2: [256][128], 8 ct x 8 ks
            int rr = r - 224; ctd = rr >> 3; ks = rr & 7; nks = 8; nc = 128; ctc = ctd;
            src = nw2 + (size_t)l * 256 * 128; dst = Bn2 + (size_t)l * 32768;
        } else {                          // ew2: [256][64], 4 ct x 8 ks
            int rr = r - 288; ctd = rr >> 3; ks = rr & 7; nks = 8; nc = 64; ctc = ctd;
            src = ew2 + (size_t)l * 256 * 64; dst = w2p + (size_t)l * 16384;
        }
    } else {                              // dw1/dw2: [128][128], 8 ct x 4 ks
        int rr = u - 1920;
        int m = rr >> 5; rr &= 31;
        ctd = rr >> 2; ks = rr & 3; nks = 4; nc = 128; ctc = ctd;
        src = m ? dw2 : dw1; dst = m ? Bd2 : Bd1;
    }
    const int k0 = ks * 32 + (lane >> 4) * 8;
    const int col = ctc * 16 + (lane & 15);
    unsigned short* o = dst + ((size_t)(ctd * nks + ks) * 64 + lane) * 8;
#pragma unroll
    for (int j = 0; j < 8; ++j)
        o[j] = f2bf(src[(size_t)(k0 + j) * nc + col]);
}

// ---------------- neighbor structure (exact top_k semantics) ----------------
__global__ __launch_bounds__(256)
void neighbor_kernel(const int* __restrict__ ei, const float* __restrict__ coords,
                     int* __restrict__ idx, float* __restrict__ rd)
{
    int i = blockIdx.x * blockDim.x + threadIdx.x;
    if (i >= NN) return;
    const int* dst = ei + (size_t)NN * KNN + (size_t)i * KNN;  // row 1 of edge_index
    int d[KNN];
    int maxd = -1;
#pragma unroll
    for (int k = 0; k < KNN; ++k) { d[k] = dst[k]; maxd = max(maxd, d[k]); }
    int sel[KNN];
    sel[0] = i;
    int pos = 1;
    bool dropped = false;
#pragma unroll
    for (int k = 0; k < KNN; ++k) {
        if (d[k] == maxd && !dropped) { dropped = true; continue; }
        if (pos < KNN) sel[pos++] = d[k];
    }
    float cx = coords[3 * i], cy = coords[3 * i + 1], cz = coords[3 * i + 2];
#pragma unroll
    for (int k = 0; k < KNN; ++k) {
        int j = sel[k];
        float dx = cx - coords[3 * j], dy = cy - coords[3 * j + 1], dz = cz - coords[3 * j + 2];
        rd[(size_t)i * KNN + k] = dx * dx + dy * dy + dz * dz;
        idx[(size_t)i * KNN + k] = j;
    }
}

// ---------------- fused edge kernel: one block per node, MFMA matvec --------
__global__ __launch_bounds__(256)
void edge_kernel(const float* __restrict__ PQ, const float* __restrict__ wr,
                 const unsigned short* __restrict__ w2p, const float* __restrict__ eb2,
                 const int* __restrict__ idx, const float* __restrict__ rd,
                 const float* __restrict__ feats, float* __restrict__ h)
{
    __shared__ unsigned short lsH[32 * 264];
    __shared__ float lsPart[2][4][16];
    __shared__ int   lsIdx[KNN];
    __shared__ float lsRd[KNN];

    const int i = blockIdx.x;
    const int t = threadIdx.x;

    if (t < KNN) { lsIdx[t] = idx[(size_t)i * KNN + t]; lsRd[t] = rd[(size_t)i * KNN + t]; }
    __syncthreads();

    {
        const int cp = (t & 127) * 2;
        const int hh = t >> 7;
        float2 p2 = *(const float2*)&PQ[(size_t)i * 512 + cp];
        float2 wv = *(const float2*)&wr[cp];
#pragma unroll
        for (int k = 0; k < 16; ++k) {
            int kk = hh * 16 + k;
            int j = lsIdx[kk];
            float rdk = lsRd[kk];
            float2 q = *(const float2*)&PQ[(size_t)j * 512 + 256 + cp];
            float a0 = silu_fast(p2.x + q.x + rdk * wv.x);
            float a1 = silu_fast(p2.y + q.y + rdk * wv.y);
            unsigned pk = ((unsigned)f2bf(a1) << 16) | (unsigned)f2bf(a0);
            *(unsigned*)&lsH[kk * 264 + cp] = pk;
        }
    }
    __syncthreads();

    const int w = t >> 6, l = t & 63;
    const int rt = w & 1, cb = (w >> 1) * 2;
    const int lr = l & 15, lg = l >> 4;
    const int arow = rt * 16 + lr;
    f32x4 acc0 = {0.f, 0.f, 0.f, 0.f}, acc1 = {0.f, 0.f, 0.f, 0.f};
#pragma unroll
    for (int ks = 0; ks < 8; ++ks) {
        bf16x8 a  = *(const bf16x8*)&lsH[arow * 264 + ks * 32 + lg * 8];
        bf16x8 b0 = *(const bf16x8*)&w2p[(size_t)(cb * 8 + ks) * 512 + l * 8];
        bf16x8 b1 = *(const bf16x8*)&w2p[(size_t)((cb + 1) * 8 + ks) * 512 + l * 8];
        acc0 = __builtin_amdgcn_mfma_f32_16x16x32_bf16(a, b0, acc0, 0, 0, 0);
        acc1 = __builtin_amdgcn_mfma_f32_16x16x32_bf16(a, b1, acc1, 0, 0, 0);
    }
    float e0 = eb2[cb * 16 + lr], e1 = eb2[(cb + 1) * 16 + lr];
    float s0 = 0.f, s1 = 0.f;
#pragma unroll
    for (int r = 0; r < 4; ++r) {
        s0 += silu_fast(acc0[r] + e0);
        s1 += silu_fast(acc1[r] + e1);
    }
    s0 += __shfl_xor(s0, 16); s0 += __shfl_xor(s0, 32);
    s1 += __shfl_xor(s1, 16); s1 += __shfl_xor(s1, 32);
    if (lg == 0) { lsPart[rt][cb][lr] = s0; lsPart[rt][cb + 1][lr] = s1; }
    __syncthreads();

    if (t < MM) {
        float m = lsPart[0][t >> 4][t & 15] + lsPart[1][t >> 4][t & 15];
        h[(size_t)i * 192 + DD + t] = m;
    } else if (t < 192) {
        h[(size_t)i * 192 + (t - 64)] = feats[(size_t)i * DD + (t - 64)];
    }
}

// ---------------- deterministic column sum (stage 1) ------------------------
__global__ __launch_bounds__(256)
void colsum_kernel(const float* __restrict__ F, float* __restrict__ partial)
{
    __shared__ float ls[2][DD];
    const int b = blockIdx.x;
    const int t = threadIdx.x;
    const int c = t & 127, rg = t >> 7;
    float s = 0.0f;
    const int r0 = b * 64;
    for (int r = rg; r < 64; r += 2) s += F[(size_t)(r0 + r) * DD + c];
    ls[rg][c] = s;
    __syncthreads();
    if (t < DD) partial[(size_t)b * DD + t] = ls[0][t] + ls[1][t];
}

// ---------------- graph decoder + normalize (single block) ------------------
__global__ __launch_bounds__(128)
void final_kernel(const float* __restrict__ partial, const float* __restrict__ gw1,
                  const float* __restrict__ gb1, const float* __restrict__ gw2,
                  const float* __restrict__ gb2, float* __restrict__ out)
{
    __shared__ float lg[DD], lu[DD], red[DD];
    const int t = threadIdx.x;
    float s = 0.0f;
    for (int b = 0; b < 96; ++b) s += partial[(size_t)b * DD + t];
    lg[t] = s;
    __syncthreads();
    float a = 0.0f;
    for (int c = 0; c < DD; ++c) a += lg[c] * gw1[(size_t)c * DD + t];
    lu[t] = silu_f(a + gb1[t]);
    __syncthreads();
    float v = 0.0f;
    for (int c = 0; c < DD; ++c) v += lu[c] * gw2[(size_t)c * DD + t];
    v += gb2[t];
    red[t] = v * v;
    __syncthreads();
    for (int sft = 64; sft > 0; sft >>= 1) {
        if (t < sft) red[t] += red[t + sft];
        __syncthreads();
    }
    float nrm = sqrtf(red[0]);
    out[t] = v / fmaxf(nrm, 1e-12f);
}

// ---------------------------------------------------------------------------
extern "C" void kernel_launch(void* const* d_in, const int* in_sizes, int n_in,
                              void* d_out, int out_size, void* d_ws, size_t ws_size,
                              hipStream_t stream)
{
    const float* x      = (const float*)d_in[0];
    const float* coords = (const float*)d_in[1];
    const int*   ei     = (const int*)d_in[2];
    const float* w_enc  = (const float*)d_in[3];
    const float* b_enc  = (const float*)d_in[4];
    const float* ew1    = (const float*)d_in[5];
    const float* eb1    = (const float*)d_in[6];
    const float* ew2    = (const float*)d_in[7];
    const float* eb2    = (const float*)d_in[8];
    const float* nw1    = (const float*)d_in[9];
    const float* nb1    = (const float*)d_in[10];
    const float* nw2    = (const float*)d_in[11];
    const float* nb2    = (const float*)d_in[12];
    const float* dw1    = (const float*)d_in[13];
    const float* db1    = (const float*)d_in[14];
    const float* dw2    = (const float*)d_in[15];
    const float* db2    = (const float*)d_in[16];
    const float* gw1    = (const float*)d_in[17];
    const float* gb1    = (const float*)d_in[18];
    const float* gw2    = (const float*)d_in[19];
    const float* gb2    = (const float*)d_in[20];
    float* out = (float*)d_out;

    // workspace layout (float units)
    float* ws      = (float*)d_ws;
    float* feats   = ws;                          // 6144*128
    float* PQ      = feats + 786432;              // 6144*512 (reused as T/U/F)
    float* hbuf    = PQ + 3145728;                // 6144*192
    int*   idxbuf  = (int*)(hbuf + 1179648);      // 6144*32
    float* rdbuf   = (float*)(idxbuf + 196608);   // 6144*32
    float* partial = rdbuf + 196608;              // 96*128
    unsigned short* w2p = (unsigned short*)(partial + 12288);  // 6*16384
    unsigned short* Bpq = w2p + 98304;            // 6*65536
    unsigned short* Bn1 = Bpq + 393216;           // 6*49152
    unsigned short* Bn2 = Bn1 + 294912;           // 6*32768
    unsigned short* Bd1 = Bn2 + 196608;           // 16384
    unsigned short* Bd2 = Bd1 + 16384;            // 16384

    float* Tbuf = PQ;
    float* Ubuf = PQ;
    float* Fbuf = PQ + 786432;

    dim3 blk(256);

    // encoder (fp32, K=68) + neighbor structure + weight packs
    gemm_kernel<<<dim3(2, 96), blk, 0, stream>>>(x, w_enc, b_enc, feats, NN, DD, 68);
    neighbor_kernel<<<24, blk, 0, stream>>>(ei, coords, idxbuf, rdbuf);
    pack_all<<<496, blk, 0, stream>>>(ew1, ew2, nw1, nw2, dw1, dw2,
                                      Bpq, Bn1, Bn2, w2p, Bd1, Bd2);

    for (int l = 0; l < NL; ++l) {
        const float* W1 = ew1 + (size_t)l * 257 * 256;
        // PQ = feats @ [ew1_fi | ew1_fj] (+eb1 on P half)
        mfma_gemm<128, false, false, true><<<dim3(8, 96), blk, 0, stream>>>(
            feats, Bpq + (size_t)l * 65536, eb1 + l * 256, PQ, 512);
        // edge second layer (MFMA) + aggregate; h = [feats, m]
        edge_kernel<<<NN, blk, 0, stream>>>(PQ, W1 + 256 * 256, w2p + (size_t)l * 16384,
                                            eb2 + l * 64, idxbuf, rdbuf, feats, hbuf);
        // T = silu(h @ nw1 + nb1)
        mfma_gemm<192, true, false, false><<<dim3(4, 96), blk, 0, stream>>>(
            hbuf, Bn1 + (size_t)l * 49152, nb1 + l * 256, Tbuf, 256);
        // feats = T @ nw2 + nb2 + feats
        mfma_gemm<256, false, true, false><<<dim3(2, 96), blk, 0, stream>>>(
            Tbuf, Bn2 + (size_t)l * 32768, nb2 + l * 128, feats, 128);
    }

    // node decoder
    mfma_gemm<128, true, false, false><<<dim3(2, 96), blk, 0, stream>>>(feats, Bd1, db1, Ubuf, 128);
    mfma_gemm<128, false, false, false><<<dim3(2, 96), blk, 0, stream>>>(Ubuf, Bd2, db2, Fbuf, 128);
    // graph sum + graph decoder + normalize
    colsum_kernel<<<96, blk, 0, stream>>>(Fbuf, partial);
    final_kernel<<<1, dim3(128), 0, stream>>>(partial, gw1, gb1, gw2, gb2, out);
}

// Round 11
// 522.083 us; speedup vs baseline: 3.8970x; 1.0846x over previous
//
#include <hip/hip_runtime.h>
#include <hip/hip_bf16.h>
#include <math.h>

// EGNN, N=6144, K=32, L=6, D=128, M=64, HE=256.
// Edge-MLP layer 1 factorizes: hidden(i,j) = silu(P[i] + Q[j] + rd_ij*wr), with
// PQ = feats @ [ew1_fi | ew1_fj] (+eb1 on P half) -> [N,512], one bf16-MFMA GEMM.
// Edge-MLP layer 2 ([32,256]@[256,64] per node) on bf16 MFMA with pre-packed ew2.
// ALL GEMMs (encoder K=68->pad96, PQ, nodeMLP1/2, node-dec) are bf16-MFMA:
// A staged fp32->bf16 in LDS (full K, stride K+8), B pre-packed fragment order.
// Neighbor selection (top_k over ranking) = {self} + 31 lowest-index adj entries
// (set equality is what matters: m_i is a sum over edges -> order-invariant).

#define NN   6144
#define KNN  32
#define NL   6
#define DD   128
#define MM   64
#define HEE  256

typedef short bf16x8 __attribute__((ext_vector_type(8)));
typedef float f32x4  __attribute__((ext_vector_type(4)));

__device__ __forceinline__ float silu_f(float x) {
    return x / (1.0f + expf(-x));
}
__device__ __forceinline__ float silu_fast(float x) {
    return __fdividef(x, 1.0f + __expf(-x));
}
__device__ __forceinline__ unsigned short f2bf(float x) {
    __hip_bfloat16 b = __float2bfloat16(x);
    return *reinterpret_cast<unsigned short*>(&b);
}
__device__ __forceinline__ unsigned pack_bf2(float lo, float hi) {
    __hip_bfloat162 v = __float22bfloat162_rn(make_float2(lo, hi));
    return *reinterpret_cast<unsigned*>(&v);
}

// ---------------- bf16 MFMA GEMM: C = [silu](A@Bp + bias) [+ C] -------------
// 64x64 tile, 4 waves (2x2), full-K A staging fp32->bf16 in LDS.
// AW = actual A row width (cols >= AW zero-padded; AW % 4 == 0).
// Bp pre-packed: Bp[((ct*NKS+ks)*64+lane)*8+j] = bf16(B[ks*32+(lane>>4)*8+j][ct*16+(lane&15)])
template<int KN, int AW, bool SILU, bool RESID, bool PQB>
__global__ __launch_bounds__(256)
void mfma_gemm(const float* __restrict__ A, const unsigned short* __restrict__ Bp,
               const float* __restrict__ bias, float* __restrict__ C, int Nn)
{
    constexpr int NKS = KN / 32;
    constexpr int LDA = KN + 8;          // row stride: 2*KN+16 bytes == 16 mod 128
    constexpr int C4  = KN / 4;
    __shared__ unsigned short lsA[64 * LDA];
    const int t = threadIdx.x;
    const int row0 = blockIdx.y * 64, col0 = blockIdx.x * 64;

#pragma unroll
    for (int u0 = 0; u0 < 64 * C4; u0 += 256) {
        int u = u0 + t;
        int r = u / C4, c4 = u % C4;
        float4 v = make_float4(0.f, 0.f, 0.f, 0.f);
        if (c4 * 4 < AW) v = *(const float4*)&A[(size_t)(row0 + r) * AW + c4 * 4];
        *(uint2*)&lsA[r * LDA + c4 * 4] = make_uint2(pack_bf2(v.x, v.y), pack_bf2(v.z, v.w));
    }
    __syncthreads();

    const int w = t >> 6, l = t & 63;
    const int wr = w & 1, wc = w >> 1;   // wave grid 2x2
    const int lr = l & 15, lg = l >> 4;
    const int ct0 = blockIdx.x * 4 + wc * 2;           // global col-tile
    const int aoff = (wr * 32 + lr) * LDA + lg * 8;
    f32x4 acc[2][2] = {};
#pragma unroll
    for (int ks = 0; ks < NKS; ++ks) {
        bf16x8 a0 = *(const bf16x8*)&lsA[aoff + ks * 32];
        bf16x8 a1 = *(const bf16x8*)&lsA[aoff + 16 * LDA + ks * 32];
        bf16x8 b0 = *(const bf16x8*)&Bp[((size_t)(ct0 * NKS + ks) * 64 + l) * 8];
        bf16x8 b1 = *(const bf16x8*)&Bp[((size_t)((ct0 + 1) * NKS + ks) * 64 + l) * 8];
        acc[0][0] = __builtin_amdgcn_mfma_f32_16x16x32_bf16(a0, b0, acc[0][0], 0, 0, 0);
        acc[0][1] = __builtin_amdgcn_mfma_f32_16x16x32_bf16(a0, b1, acc[0][1], 0, 0, 0);
        acc[1][0] = __builtin_amdgcn_mfma_f32_16x16x32_bf16(a1, b0, acc[1][0], 0, 0, 0);
        acc[1][1] = __builtin_amdgcn_mfma_f32_16x16x32_bf16(a1, b1, acc[1][1], 0, 0, 0);
    }
#pragma unroll
    for (int rt = 0; rt < 2; ++rt) {
#pragma unroll
        for (int ctl = 0; ctl < 2; ++ctl) {
            int col = col0 + wc * 32 + ctl * 16 + lr;
            float bv = (!PQB || col < 256) ? bias[col] : 0.0f;
#pragma unroll
            for (int r = 0; r < 4; ++r) {
                int row = row0 + wr * 32 + rt * 16 + lg * 4 + r;
                float v = acc[rt][ctl][r] + bv;
                if (SILU) v = silu_f(v);
                size_t off = (size_t)row * Nn + col;
                if (RESID) v += C[off];
                C[off] = v;
            }
        }
    }
}

// ---------------- unified weight pre-pack (all layers, all matrices) --------
// 2008 units of (matrix, ct, ks); unit -> 64 lanes x 8 bf16.
__global__ __launch_bounds__(256)
void pack_all(const float* __restrict__ ew1, const float* __restrict__ ew2,
              const float* __restrict__ nw1, const float* __restrict__ nw2,
              const float* __restrict__ dw1, const float* __restrict__ dw2,
              const float* __restrict__ wenc,
              unsigned short* __restrict__ Bpq, unsigned short* __restrict__ Bn1,
              unsigned short* __restrict__ Bn2, unsigned short* __restrict__ w2p,
              unsigned short* __restrict__ Bd1, unsigned short* __restrict__ Bd2,
              unsigned short* __restrict__ Benc)
{
    const int t = threadIdx.x;
    const int u = blockIdx.x * 4 + (t >> 6);
    if (u >= 2008) return;
    const int lane = t & 63;
    const float* src; unsigned short* dst;
    int nks, nc, ctd, ctc, ks, kmax = 1 << 30;
    if (u < 1920) {
        int l = u / 320, r = u % 320;
        if (r < 128) {                    // PQ: ew1 split-source, 32 ct x 4 ks
            ctd = r >> 2; ks = r & 3; nks = 4; nc = 256; ctc = ctd & 15;
            src = ew1 + (size_t)l * 257 * 256 + (ctd >= 16 ? 128 * 256 : 0);
            dst = Bpq + (size_t)l * 65536;
        } else if (r < 224) {             // n1: [192][256], 16 ct x 6 ks
            int rr = r - 128; ctd = rr / 6; ks = rr % 6; nks = 6; nc = 256; ctc = ctd;
            src = nw1 + (size_t)l * 192 * 256; dst = Bn1 + (size_t)l * 49152;
        } else if (r < 288) {             // n2: [256][128], 8 ct x 8 ks
            int rr = r - 224; ctd = rr >> 3; ks = rr & 7; nks = 8; nc = 128; ctc = ctd;
            src = nw2 + (size_t)l * 256 * 128; dst = Bn2 + (size_t)l * 32768;
        } else {                          // ew2: [256][64], 4 ct x 8 ks
            int rr = r - 288; ctd = rr >> 3; ks = rr & 7; nks = 8; nc = 64; ctc = ctd;
            src = ew2 + (size_t)l * 256 * 64; dst = w2p + (size_t)l * 16384;
        }
    } else if (u < 1984) {                // dw1/dw2: [128][128], 8 ct x 4 ks
        int rr = u - 1920;
        int m = rr >> 5; rr &= 31;
        ctd = rr >> 2; ks = rr & 3; nks = 4; nc = 128; ctc = ctd;
        src = m ? dw2 : dw1; dst = m ? Bd2 : Bd1;
    } else {                              // encoder: [68][128] pad K->96, 8 ct x 3 ks
        int rr = u - 1984;
        ctd = rr / 3; ks = rr % 3; nks = 3; nc = 128; ctc = ctd; kmax = 68;
        src = wenc; dst = Benc;
    }
    const int k0 = ks * 32 + (lane >> 4) * 8;
    const int col = ctc * 16 + (lane & 15);
    unsigned short* o = dst + ((size_t)(ctd * nks + ks) * 64 + lane) * 8;
#pragma unroll
    for (int j = 0; j < 8; ++j)
        o[j] = (k0 + j < kmax) ? f2bf(src[(size_t)(k0 + j) * nc + col]) : (unsigned short)0;
}

// ---------------- neighbor structure: thread = (node, k) edge slot ----------
// Per 32-lane group: argmax over dst indices (distinct), drop it, self at slot 0.
// Output order differs from jax top_k but the edge set is identical and m_i is
// an order-invariant sum.
__global__ __launch_bounds__(256)
void neighbor_kernel(const int* __restrict__ ei, const float* __restrict__ coords,
                     int* __restrict__ idx, float* __restrict__ rd)
{
    const int gid = blockIdx.x * 256 + threadIdx.x;   // 768 blocks -> NN*32 exact
    const int i = gid >> 5, k = gid & 31;
    const int j = ei[(size_t)NN * KNN + (size_t)i * KNN + k];
    int dmax = j, kmax = k;
#pragma unroll
    for (int m = 1; m < 32; m <<= 1) {
        int od = __shfl_xor(dmax, m);
        int ok = __shfl_xor(kmax, m);
        if (od > dmax) { dmax = od; kmax = ok; }
    }
    int pos, jw;
    if (k == kmax) { pos = 0; jw = i; }
    else { pos = (k < kmax) ? k + 1 : k; jw = j; }
    float dx = coords[3 * i]     - coords[3 * jw];
    float dy = coords[3 * i + 1] - coords[3 * jw + 1];
    float dz = coords[3 * i + 2] - coords[3 * jw + 2];
    rd[(size_t)i * KNN + pos]  = dx * dx + dy * dy + dz * dz;
    idx[(size_t)i * KNN + pos] = jw;
}

// ---------------- fused edge kernel: one block per node, MFMA matvec --------
// Phase A: hidden[k][c] = silu(P[i][c] + Q[j_k][c] + rd_k*wr[c]) -> bf16 LDS,
//   thread = 4 cols x 8 rows, all 8 gathered Q rows prefetched to registers.
// Phase B: [32,256]@[256,64] via MFMA; silu; k-reduce -> m_i; h=[feats,m].
__global__ __launch_bounds__(256)
void edge_kernel(const float* __restrict__ PQ, const float* __restrict__ wr,
                 const unsigned short* __restrict__ w2p, const float* __restrict__ eb2,
                 const int* __restrict__ idx, const float* __restrict__ rd,
                 const float* __restrict__ feats, float* __restrict__ h)
{
    __shared__ unsigned short lsH[32 * 264];
    __shared__ float lsPart[2][4][16];
    __shared__ int   lsIdx[KNN];
    __shared__ float lsRd[KNN];

    const int i = blockIdx.x;
    const int t = threadIdx.x;

    if (t < KNN) { lsIdx[t] = idx[(size_t)i * KNN + t]; lsRd[t] = rd[(size_t)i * KNN + t]; }
    __syncthreads();

    // Phase A
    {
        const int c0 = (t & 63) * 4;
        const int rg = t >> 6;
        float4 p4 = *(const float4*)&PQ[(size_t)i * 512 + c0];
        float4 w4 = *(const float4*)&wr[c0];
        int   jj[8]; float rr[8];
#pragma unroll
        for (int k = 0; k < 8; ++k) { jj[k] = lsIdx[rg * 8 + k]; rr[k] = lsRd[rg * 8 + k]; }
        float4 q[8];
#pragma unroll
        for (int k = 0; k < 8; ++k)
            q[k] = *(const float4*)&PQ[(size_t)jj[k] * 512 + 256 + c0];
#pragma unroll
        for (int k = 0; k < 8; ++k) {
            float a0 = silu_fast(fmaf(rr[k], w4.x, p4.x) + q[k].x);
            float a1 = silu_fast(fmaf(rr[k], w4.y, p4.y) + q[k].y);
            float a2 = silu_fast(fmaf(rr[k], w4.z, p4.z) + q[k].z);
            float a3 = silu_fast(fmaf(rr[k], w4.w, p4.w) + q[k].w);
            *(uint2*)&lsH[(rg * 8 + k) * 264 + c0] =
                make_uint2(pack_bf2(a0, a1), pack_bf2(a2, a3));
        }
    }
    __syncthreads();

    // Phase B
    const int w = t >> 6, l = t & 63;
    const int rt = w & 1, cb = (w >> 1) * 2;
    const int lr = l & 15, lg = l >> 4;
    const int arow = rt * 16 + lr;
    f32x4 acc0 = {0.f, 0.f, 0.f, 0.f}, acc1 = {0.f, 0.f, 0.f, 0.f};
#pragma unroll
    for (int ks = 0; ks < 8; ++ks) {
        bf16x8 a  = *(const bf16x8*)&lsH[arow * 264 + ks * 32 + lg * 8];
        bf16x8 b0 = *(const bf16x8*)&w2p[(size_t)(cb * 8 + ks) * 512 + l * 8];
        bf16x8 b1 = *(const bf16x8*)&w2p[(size_t)((cb + 1) * 8 + ks) * 512 + l * 8];
        acc0 = __builtin_amdgcn_mfma_f32_16x16x32_bf16(a, b0, acc0, 0, 0, 0);
        acc1 = __builtin_amdgcn_mfma_f32_16x16x32_bf16(a, b1, acc1, 0, 0, 0);
    }
    float e0 = eb2[cb * 16 + lr], e1 = eb2[(cb + 1) * 16 + lr];
    float s0 = 0.f, s1 = 0.f;
#pragma unroll
    for (int r = 0; r < 4; ++r) {
        s0 += silu_fast(acc0[r] + e0);
        s1 += silu_fast(acc1[r] + e1);
    }
    s0 += __shfl_xor(s0, 16); s0 += __shfl_xor(s0, 32);
    s1 += __shfl_xor(s1, 16); s1 += __shfl_xor(s1, 32);
    if (lg == 0) { lsPart[rt][cb][lr] = s0; lsPart[rt][cb + 1][lr] = s1; }
    __syncthreads();

    if (t < MM) {
        float m = lsPart[0][t >> 4][t & 15] + lsPart[1][t >> 4][t & 15];
        h[(size_t)i * 192 + DD + t] = m;
    } else if (t < 192) {
        h[(size_t)i * 192 + (t - 64)] = feats[(size_t)i * DD + (t - 64)];
    }
}

// ---------------- deterministic column sum (stage 1) ------------------------
__global__ __launch_bounds__(256)
void colsum_kernel(const float* __restrict__ F, float* __restrict__ partial)
{
    __shared__ float ls[2][DD];
    const int b = blockIdx.x;
    const int t = threadIdx.x;
    const int c = t & 127, rg = t >> 7;
    float s = 0.0f;
    const int r0 = b * 64;
    for (int r = rg; r < 64; r += 2) s += F[(size_t)(r0 + r) * DD + c];
    ls[rg][c] = s;
    __syncthreads();
    if (t < DD) partial[(size_t)b * DD + t] = ls[0][t] + ls[1][t];
}

// ---------------- graph decoder + normalize (single block) ------------------
__global__ __launch_bounds__(128)
void final_kernel(const float* __restrict__ partial, const float* __restrict__ gw1,
                  const float* __restrict__ gb1, const float* __restrict__ gw2,
                  const float* __restrict__ gb2, float* __restrict__ out)
{
    __shared__ float lg[DD], lu[DD], red[DD];
    const int t = threadIdx.x;
    float s = 0.0f;
    for (int b = 0; b < 96; ++b) s += partial[(size_t)b * DD + t];
    lg[t] = s;
    __syncthreads();
    float a = 0.0f;
    for (int c = 0; c < DD; ++c) a += lg[c] * gw1[(size_t)c * DD + t];
    lu[t] = silu_f(a + gb1[t]);
    __syncthreads();
    float v = 0.0f;
    for (int c = 0; c < DD; ++c) v += lu[c] * gw2[(size_t)c * DD + t];
    v += gb2[t];
    red[t] = v * v;
    __syncthreads();
    for (int sft = 64; sft > 0; sft >>= 1) {
        if (t < sft) red[t] += red[t + sft];
        __syncthreads();
    }
    float nrm = sqrtf(red[0]);
    out[t] = v / fmaxf(nrm, 1e-12f);
}

// ---------------------------------------------------------------------------
extern "C" void kernel_launch(void* const* d_in, const int* in_sizes, int n_in,
                              void* d_out, int out_size, void* d_ws, size_t ws_size,
                              hipStream_t stream)
{
    const float* x      = (const float*)d_in[0];
    const float* coords = (const float*)d_in[1];
    const int*   ei     = (const int*)d_in[2];
    const float* w_enc  = (const float*)d_in[3];
    const float* b_enc  = (const float*)d_in[4];
    const float* ew1    = (const float*)d_in[5];
    const float* eb1    = (const float*)d_in[6];
    const float* ew2    = (const float*)d_in[7];
    const float* eb2    = (const float*)d_in[8];
    const float* nw1    = (const float*)d_in[9];
    const float* nb1    = (const float*)d_in[10];
    const float* nw2    = (const float*)d_in[11];
    const float* nb2    = (const float*)d_in[12];
    const float* dw1    = (const float*)d_in[13];
    const float* db1    = (const float*)d_in[14];
    const float* dw2    = (const float*)d_in[15];
    const float* db2    = (const float*)d_in[16];
    const float* gw1    = (const float*)d_in[17];
    const float* gb1    = (const float*)d_in[18];
    const float* gw2    = (const float*)d_in[19];
    const float* gb2    = (const float*)d_in[20];
    float* out = (float*)d_out;

    // workspace layout (float units)
    float* ws      = (float*)d_ws;
    float* feats   = ws;                          // 6144*128
    float* PQ      = feats + 786432;              // 6144*512 (reused as T/U/F)
    float* hbuf    = PQ + 3145728;                // 6144*192
    int*   idxbuf  = (int*)(hbuf + 1179648);      // 6144*32
    float* rdbuf   = (float*)(idxbuf + 196608);   // 6144*32
    float* partial = rdbuf + 196608;              // 96*128
    unsigned short* w2p  = (unsigned short*)(partial + 12288);  // 6*16384
    unsigned short* Bpq  = w2p + 98304;           // 6*65536
    unsigned short* Bn1  = Bpq + 393216;          // 6*49152
    unsigned short* Bn2  = Bn1 + 294912;          // 6*32768
    unsigned short* Bd1  = Bn2 + 196608;          // 16384
    unsigned short* Bd2  = Bd1 + 16384;           // 16384
    unsigned short* Benc = Bd2 + 16384;           // 24*64*8 = 12288

    float* Tbuf = PQ;
    float* Ubuf = PQ;
    float* Fbuf = PQ + 786432;

    dim3 blk(256);

    // neighbor structure + weight packs + encoder (MFMA, K=68 padded to 96)
    neighbor_kernel<<<768, blk, 0, stream>>>(ei, coords, idxbuf, rdbuf);
    pack_all<<<502, blk, 0, stream>>>(ew1, ew2, nw1, nw2, dw1, dw2, w_enc,
                                      Bpq, Bn1, Bn2, w2p, Bd1, Bd2, Benc);
    mfma_gemm<96, 68, false, false, false><<<dim3(2, 96), blk, 0, stream>>>(
        x, Benc, b_enc, feats, 128);

    for (int l = 0; l < NL; ++l) {
        const float* W1 = ew1 + (size_t)l * 257 * 256;
        // PQ = feats @ [ew1_fi | ew1_fj] (+eb1 on P half)
        mfma_gemm<128, 128, false, false, true><<<dim3(8, 96), blk, 0, stream>>>(
            feats, Bpq + (size_t)l * 65536, eb1 + l * 256, PQ, 512);
        // edge second layer (MFMA) + aggregate; h = [feats, m]
        edge_kernel<<<NN, blk, 0, stream>>>(PQ, W1 + 256 * 256, w2p + (size_t)l * 16384,
                                            eb2 + l * 64, idxbuf, rdbuf, feats, hbuf);
        // T = silu(h @ nw1 + nb1)
        mfma_gemm<192, 192, true, false, false><<<dim3(4, 96), blk, 0, stream>>>(
            hbuf, Bn1 + (size_t)l * 49152, nb1 + l * 256, Tbuf, 256);
        // feats = T @ nw2 + nb2 + feats
        mfma_gemm<256, 256, false, true, false><<<dim3(2, 96), blk, 0, stream>>>(
            Tbuf, Bn2 + (size_t)l * 32768, nb2 + l * 128, feats, 128);
    }

    // node decoder
    mfma_gemm<128, 128, true, false, false><<<dim3(2, 96), blk, 0, stream>>>(feats, Bd1, db1, Ubuf, 128);
    mfma_gemm<128, 128, false, false, false><<<dim3(2, 96), blk, 0, stream>>>(Ubuf, Bd2, db2, Fbuf, 128);
    // graph sum + graph decoder + normalize
    colsum_kernel<<<96, blk, 0, stream>>>(Fbuf, partial);
    final_kernel<<<1, dim3(128), 0, stream>>>(partial, gw1, gb1, gw2, gb2, out);
}

// Round 12
// 464.728 us; speedup vs baseline: 4.3779x; 1.1234x over previous
//
#include <hip/hip_runtime.h>
#include <hip/hip_bf16.h>
#include <math.h>

// EGNN, N=6144, K=32, L=6, D=128, M=64, HE=256.
// Layer pipeline (2 dispatches/layer):
//   edge_kernel: hidden=silu(P+Q+rd*wr) -> MFMA [32,256]@[256,64] -> m  (per node)
//   node_mlp:    T=silu([feats|m]@nw1+nb1) -> feats=T@nw2+nb2+feats
//                -> PQ_next = feats@[ew1_fi|ew1_fj] (+eb1)   (fused, LDS-resident)
// All matmuls bf16-MFMA (16x16x32), weights pre-packed to B-fragment order.
// Neighbor selection (top_k over ranking) = {self} + 31 lowest-index adj entries
// (edge set equality; m_i is an order-invariant sum).

#define NN   6144
#define KNN  32
#define NL   6
#define DD   128
#define MM   64
#define HEE  256

typedef short bf16x8 __attribute__((ext_vector_type(8)));
typedef float f32x4  __attribute__((ext_vector_type(4)));

__device__ __forceinline__ float silu_f(float x) {
    return x / (1.0f + expf(-x));
}
__device__ __forceinline__ float silu_fast(float x) {
    return __fdividef(x, 1.0f + __expf(-x));
}
__device__ __forceinline__ unsigned short f2bf(float x) {
    __hip_bfloat16 b = __float2bfloat16(x);
    return *reinterpret_cast<unsigned short*>(&b);
}
__device__ __forceinline__ unsigned pack_bf2(float lo, float hi) {
    __hip_bfloat162 v = __float22bfloat162_rn(make_float2(lo, hi));
    return *reinterpret_cast<unsigned*>(&v);
}

// ---------------- bf16 MFMA GEMM (encoder + layer-0 PQ only) ----------------
// 64x64 tile, 4 waves (2x2), full-K A staging fp32->bf16 in LDS.
template<int KN, int AW, bool SILU, bool RESID, bool PQB>
__global__ __launch_bounds__(256)
void mfma_gemm(const float* __restrict__ A, const unsigned short* __restrict__ Bp,
               const float* __restrict__ bias, float* __restrict__ C, int Nn)
{
    constexpr int NKS = KN / 32;
    constexpr int LDA = KN + 8;
    constexpr int C4  = KN / 4;
    __shared__ unsigned short lsA[64 * LDA];
    const int t = threadIdx.x;
    const int row0 = blockIdx.y * 64, col0 = blockIdx.x * 64;

#pragma unroll
    for (int u0 = 0; u0 < 64 * C4; u0 += 256) {
        int u = u0 + t;
        int r = u / C4, c4 = u % C4;
        float4 v = make_float4(0.f, 0.f, 0.f, 0.f);
        if (c4 * 4 < AW) v = *(const float4*)&A[(size_t)(row0 + r) * AW + c4 * 4];
        *(uint2*)&lsA[r * LDA + c4 * 4] = make_uint2(pack_bf2(v.x, v.y), pack_bf2(v.z, v.w));
    }
    __syncthreads();

    const int w = t >> 6, l = t & 63;
    const int wr = w & 1, wc = w >> 1;
    const int lr = l & 15, lg = l >> 4;
    const int ct0 = blockIdx.x * 4 + wc * 2;
    const int aoff = (wr * 32 + lr) * LDA + lg * 8;
    f32x4 acc[2][2] = {};
#pragma unroll
    for (int ks = 0; ks < NKS; ++ks) {
        bf16x8 a0 = *(const bf16x8*)&lsA[aoff + ks * 32];
        bf16x8 a1 = *(const bf16x8*)&lsA[aoff + 16 * LDA + ks * 32];
        bf16x8 b0 = *(const bf16x8*)&Bp[((size_t)(ct0 * NKS + ks) * 64 + l) * 8];
        bf16x8 b1 = *(const bf16x8*)&Bp[((size_t)((ct0 + 1) * NKS + ks) * 64 + l) * 8];
        acc[0][0] = __builtin_amdgcn_mfma_f32_16x16x32_bf16(a0, b0, acc[0][0], 0, 0, 0);
        acc[0][1] = __builtin_amdgcn_mfma_f32_16x16x32_bf16(a0, b1, acc[0][1], 0, 0, 0);
        acc[1][0] = __builtin_amdgcn_mfma_f32_16x16x32_bf16(a1, b0, acc[1][0], 0, 0, 0);
        acc[1][1] = __builtin_amdgcn_mfma_f32_16x16x32_bf16(a1, b1, acc[1][1], 0, 0, 0);
    }
#pragma unroll
    for (int rt = 0; rt < 2; ++rt) {
#pragma unroll
        for (int ctl = 0; ctl < 2; ++ctl) {
            int col = col0 + wc * 32 + ctl * 16 + lr;
            float bv = (!PQB || col < 256) ? bias[col] : 0.0f;
#pragma unroll
            for (int r = 0; r < 4; ++r) {
                int row = row0 + wr * 32 + rt * 16 + lg * 4 + r;
                float v = acc[rt][ctl][r] + bv;
                if (SILU) v = silu_f(v);
                size_t off = (size_t)row * Nn + col;
                if (RESID) v += C[off];
                C[off] = v;
            }
        }
    }
}

// ---------------- fused node MLP (+ optional next-layer PQ) -----------------
// 32-node strip per block, 4 waves. KA=192: A=[feats|m]; KA=128: A=feats.
// T = silu(A@B1+b1) [32,KH] in LDS; out = T@B2+b2 (+feats resid) -> outF;
// PQOUT: PQ = out@Bpq (+eb1 on cols<256) -> [32,512].
template<int KA, int KH, bool RESID, bool PQOUT>
__global__ __launch_bounds__(256, 4)
void node_mlp(const float* __restrict__ feats, const float* __restrict__ mbuf,
              const unsigned short* __restrict__ B1, const float* __restrict__ b1,
              const unsigned short* __restrict__ B2, const float* __restrict__ b2,
              const unsigned short* __restrict__ Bpq, const float* __restrict__ eb1,
              float* __restrict__ outF, float* __restrict__ PQ)
{
    constexpr int LDA = KA + 8;
    constexpr int LDT = KH + 8;
    constexpr int KS1 = KA / 32;
    constexpr int KS2 = KH / 32;
    constexpr int CT1 = KH / 64;         // T col-tiles per wave
    constexpr int C4A = KA / 4;
    __shared__ unsigned short lsA[32 * LDA];
    __shared__ unsigned short lsT[32 * LDT];
    __shared__ unsigned short lsF[PQOUT ? 32 * 136 : 4];
    const int t = threadIdx.x;
    const int r0 = blockIdx.x * 32;

    // stage A rows r0..r0+31 fp32->bf16 ([feats(128) | m(64)] for KA=192)
#pragma unroll
    for (int u0 = 0; u0 < 32 * C4A; u0 += 256) {
        int u = u0 + t;
        int r = u / C4A, c = (u % C4A) * 4;
        float4 v;
        if (KA == 128 || c < 128) v = *(const float4*)&feats[(size_t)(r0 + r) * DD + c];
        else                      v = *(const float4*)&mbuf[(size_t)(r0 + r) * MM + (c - 128)];
        *(uint2*)&lsA[r * LDA + c] = make_uint2(pack_bf2(v.x, v.y), pack_bf2(v.z, v.w));
    }
    __syncthreads();

    const int w = t >> 6, l = t & 63;
    const int lr = l & 15, lg = l >> 4;

    // ---- n1: T = silu(A@B1 + b1) ----
    {
        f32x4 acc[2][CT1] = {};
#pragma unroll
        for (int ks = 0; ks < KS1; ++ks) {
            bf16x8 a0 = *(const bf16x8*)&lsA[lr * LDA + ks * 32 + lg * 8];
            bf16x8 a1 = *(const bf16x8*)&lsA[(16 + lr) * LDA + ks * 32 + lg * 8];
#pragma unroll
            for (int ct = 0; ct < CT1; ++ct) {
                bf16x8 b = *(const bf16x8*)&B1[((size_t)((w * CT1 + ct) * KS1 + ks) * 64 + l) * 8];
                acc[0][ct] = __builtin_amdgcn_mfma_f32_16x16x32_bf16(a0, b, acc[0][ct], 0, 0, 0);
                acc[1][ct] = __builtin_amdgcn_mfma_f32_16x16x32_bf16(a1, b, acc[1][ct], 0, 0, 0);
            }
        }
#pragma unroll
        for (int rt = 0; rt < 2; ++rt)
#pragma unroll
        for (int ct = 0; ct < CT1; ++ct) {
            int col = (w * CT1 + ct) * 16 + lr;
            float bv = b1[col];
#pragma unroll
            for (int r = 0; r < 4; ++r) {
                int row = rt * 16 + lg * 4 + r;
                lsT[row * LDT + col] = f2bf(silu_f(acc[rt][ct][r] + bv));
            }
        }
    }
    __syncthreads();

    // ---- n2: out = T@B2 + b2 (+resid) ----
    {
        f32x4 acc[2][2] = {};
#pragma unroll
        for (int ks = 0; ks < KS2; ++ks) {
            bf16x8 a0 = *(const bf16x8*)&lsT[lr * LDT + ks * 32 + lg * 8];
            bf16x8 a1 = *(const bf16x8*)&lsT[(16 + lr) * LDT + ks * 32 + lg * 8];
#pragma unroll
            for (int ct = 0; ct < 2; ++ct) {
                bf16x8 b = *(const bf16x8*)&B2[((size_t)((w * 2 + ct) * KS2 + ks) * 64 + l) * 8];
                acc[0][ct] = __builtin_amdgcn_mfma_f32_16x16x32_bf16(a0, b, acc[0][ct], 0, 0, 0);
                acc[1][ct] = __builtin_amdgcn_mfma_f32_16x16x32_bf16(a1, b, acc[1][ct], 0, 0, 0);
            }
        }
#pragma unroll
        for (int rt = 0; rt < 2; ++rt)
#pragma unroll
        for (int ct = 0; ct < 2; ++ct) {
            int col = (w * 2 + ct) * 16 + lr;
            float bv = b2[col];
#pragma unroll
            for (int r = 0; r < 4; ++r) {
                int row = rt * 16 + lg * 4 + r;
                size_t off = (size_t)(r0 + row) * DD + col;
                float v = acc[rt][ct][r] + bv;
                if (RESID) v += feats[off];
                outF[off] = v;
                if (PQOUT) lsF[row * 136 + col] = f2bf(v);
            }
        }
    }

    // ---- PQ for next layer: PQ = out@Bpq (+eb1 on P half) ----
    if (PQOUT) {
        __syncthreads();
#pragma unroll
        for (int cp = 0; cp < 2; ++cp) {
            f32x4 acc[2][4] = {};
#pragma unroll
            for (int ks = 0; ks < 4; ++ks) {
                bf16x8 a0 = *(const bf16x8*)&lsF[lr * 136 + ks * 32 + lg * 8];
                bf16x8 a1 = *(const bf16x8*)&lsF[(16 + lr) * 136 + ks * 32 + lg * 8];
#pragma unroll
                for (int ct = 0; ct < 4; ++ct) {
                    int ctg = w * 8 + cp * 4 + ct;
                    bf16x8 b = *(const bf16x8*)&Bpq[((size_t)(ctg * 4 + ks) * 64 + l) * 8];
                    acc[0][ct] = __builtin_amdgcn_mfma_f32_16x16x32_bf16(a0, b, acc[0][ct], 0, 0, 0);
                    acc[1][ct] = __builtin_amdgcn_mfma_f32_16x16x32_bf16(a1, b, acc[1][ct], 0, 0, 0);
                }
            }
#pragma unroll
            for (int rt = 0; rt < 2; ++rt)
#pragma unroll
            for (int ct = 0; ct < 4; ++ct) {
                int col = (w * 8 + cp * 4 + ct) * 16 + lr;
                float bv = (col < 256) ? eb1[col] : 0.0f;
#pragma unroll
                for (int r = 0; r < 4; ++r) {
                    int row = rt * 16 + lg * 4 + r;
                    PQ[(size_t)(r0 + row) * 512 + col] = acc[rt][ct][r] + bv;
                }
            }
        }
    }
}

// ---------------- unified weight pre-pack (unchanged layouts) ---------------
__global__ __launch_bounds__(256)
void pack_all(const float* __restrict__ ew1, const float* __restrict__ ew2,
              const float* __restrict__ nw1, const float* __restrict__ nw2,
              const float* __restrict__ dw1, const float* __restrict__ dw2,
              const float* __restrict__ wenc,
              unsigned short* __restrict__ Bpq, unsigned short* __restrict__ Bn1,
              unsigned short* __restrict__ Bn2, unsigned short* __restrict__ w2p,
              unsigned short* __restrict__ Bd1, unsigned short* __restrict__ Bd2,
              unsigned short* __restrict__ Benc)
{
    const int t = threadIdx.x;
    const int u = blockIdx.x * 4 + (t >> 6);
    if (u >= 2008) return;
    const int lane = t & 63;
    const float* src; unsigned short* dst;
    int nks, nc, ctd, ctc, ks, kmax = 1 << 30;
    if (u < 1920) {
        int l = u / 320, r = u % 320;
        if (r < 128) {                    // PQ: ew1 split-source, 32 ct x 4 ks
            ctd = r >> 2; ks = r & 3; nks = 4; nc = 256; ctc = ctd & 15;
            src = ew1 + (size_t)l * 257 * 256 + (ctd >= 16 ? 128 * 256 : 0);
            dst = Bpq + (size_t)l * 65536;
        } else if (r < 224) {             // n1: [192][256], 16 ct x 6 ks
            int rr = r - 128; ctd = rr / 6; ks = rr % 6; nks = 6; nc = 256; ctc = ctd;
            src = nw1 + (size_t)l * 192 * 256; dst = Bn1 + (size_t)l * 49152;
        } else if (r < 288) {             // n2: [256][128], 8 ct x 8 ks
            int rr = r - 224; ctd = rr >> 3; ks = rr & 7; nks = 8; nc = 128; ctc = ctd;
            src = nw2 + (size_t)l * 256 * 128; dst = Bn2 + (size_t)l * 32768;
        } else {                          // ew2: [256][64], 4 ct x 8 ks
            int rr = r - 288; ctd = rr >> 3; ks = rr & 7; nks = 8; nc = 64; ctc = ctd;
            src = ew2 + (size_t)l * 256 * 64; dst = w2p + (size_t)l * 16384;
        }
    } else if (u < 1984) {                // dw1/dw2: [128][128], 8 ct x 4 ks
        int rr = u - 1920;
        int m = rr >> 5; rr &= 31;
        ctd = rr >> 2; ks = rr & 3; nks = 4; nc = 128; ctc = ctd;
        src = m ? dw2 : dw1; dst = m ? Bd2 : Bd1;
    } else {                              // encoder: [68][128] pad K->96, 8 ct x 3 ks
        int rr = u - 1984;
        ctd = rr / 3; ks = rr % 3; nks = 3; nc = 128; ctc = ctd; kmax = 68;
        src = wenc; dst = Benc;
    }
    const int k0 = ks * 32 + (lane >> 4) * 8;
    const int col = ctc * 16 + (lane & 15);
    unsigned short* o = dst + ((size_t)(ctd * nks + ks) * 64 + lane) * 8;
#pragma unroll
    for (int j = 0; j < 8; ++j)
        o[j] = (k0 + j < kmax) ? f2bf(src[(size_t)(k0 + j) * nc + col]) : (unsigned short)0;
}

// ---------------- neighbor structure: thread = (node, k) edge slot ----------
__global__ __launch_bounds__(256)
void neighbor_kernel(const int* __restrict__ ei, const float* __restrict__ coords,
                     int* __restrict__ idx, float* __restrict__ rd)
{
    const int gid = blockIdx.x * 256 + threadIdx.x;
    const int i = gid >> 5, k = gid & 31;
    const int j = ei[(size_t)NN * KNN + (size_t)i * KNN + k];
    int dmax = j, kmax = k;
#pragma unroll
    for (int m = 1; m < 32; m <<= 1) {
        int od = __shfl_xor(dmax, m);
        int ok = __shfl_xor(kmax, m);
        if (od > dmax) { dmax = od; kmax = ok; }
    }
    int pos, jw;
    if (k == kmax) { pos = 0; jw = i; }
    else { pos = (k < kmax) ? k + 1 : k; jw = j; }
    float dx = coords[3 * i]     - coords[3 * jw];
    float dy = coords[3 * i + 1] - coords[3 * jw + 1];
    float dz = coords[3 * i + 2] - coords[3 * jw + 2];
    rd[(size_t)i * KNN + pos]  = dx * dx + dy * dy + dz * dz;
    idx[(size_t)i * KNN + pos] = jw;
}

// ---------------- fused edge kernel: one block per node, MFMA matvec --------
// Phase A: hidden = silu(P+Q+rd*wr) -> bf16 LDS (8 gathered rows prefetched,
// sched_barrier pins loads before compute). Phase B: MFMA + k-reduce -> m.
__global__ __launch_bounds__(256)
void edge_kernel(const float* __restrict__ PQ, const float* __restrict__ wr,
                 const unsigned short* __restrict__ w2p, const float* __restrict__ eb2,
                 const int* __restrict__ idx, const float* __restrict__ rd,
                 float* __restrict__ mbuf)
{
    __shared__ unsigned short lsH[32 * 264];
    __shared__ float lsPart[2][4][16];
    __shared__ int   lsIdx[KNN];
    __shared__ float lsRd[KNN];

    const int i = blockIdx.x;
    const int t = threadIdx.x;

    if (t < KNN) { lsIdx[t] = idx[(size_t)i * KNN + t]; lsRd[t] = rd[(size_t)i * KNN + t]; }
    __syncthreads();

    // Phase A
    {
        const int c0 = (t & 63) * 4;
        const int rg = t >> 6;
        float4 p4 = *(const float4*)&PQ[(size_t)i * 512 + c0];
        float4 w4 = *(const float4*)&wr[c0];
        int   jj[8]; float rr[8];
#pragma unroll
        for (int k = 0; k < 8; ++k) { jj[k] = lsIdx[rg * 8 + k]; rr[k] = lsRd[rg * 8 + k]; }
        float4 q[8];
#pragma unroll
        for (int k = 0; k < 8; ++k)
            q[k] = *(const float4*)&PQ[(size_t)jj[k] * 512 + 256 + c0];
        __builtin_amdgcn_sched_barrier(0);   // keep all 8 gathers issued before compute
#pragma unroll
        for (int k = 0; k < 8; ++k) {
            float a0 = silu_fast(fmaf(rr[k], w4.x, p4.x) + q[k].x);
            float a1 = silu_fast(fmaf(rr[k], w4.y, p4.y) + q[k].y);
            float a2 = silu_fast(fmaf(rr[k], w4.z, p4.z) + q[k].z);
            float a3 = silu_fast(fmaf(rr[k], w4.w, p4.w) + q[k].w);
            *(uint2*)&lsH[(rg * 8 + k) * 264 + c0] =
                make_uint2(pack_bf2(a0, a1), pack_bf2(a2, a3));
        }
    }
    __syncthreads();

    // Phase B
    const int w = t >> 6, l = t & 63;
    const int rt = w & 1, cb = (w >> 1) * 2;
    const int lr = l & 15, lg = l >> 4;
    const int arow = rt * 16 + lr;
    f32x4 acc0 = {0.f, 0.f, 0.f, 0.f}, acc1 = {0.f, 0.f, 0.f, 0.f};
#pragma unroll
    for (int ks = 0; ks < 8; ++ks) {
        bf16x8 a  = *(const bf16x8*)&lsH[arow * 264 + ks * 32 + lg * 8];
        bf16x8 b0 = *(const bf16x8*)&w2p[(size_t)(cb * 8 + ks) * 512 + l * 8];
        bf16x8 b1 = *(const bf16x8*)&w2p[(size_t)((cb + 1) * 8 + ks) * 512 + l * 8];
        acc0 = __builtin_amdgcn_mfma_f32_16x16x32_bf16(a, b0, acc0, 0, 0, 0);
        acc1 = __builtin_amdgcn_mfma_f32_16x16x32_bf16(a, b1, acc1, 0, 0, 0);
    }
    float e0 = eb2[cb * 16 + lr], e1 = eb2[(cb + 1) * 16 + lr];
    float s0 = 0.f, s1 = 0.f;
#pragma unroll
    for (int r = 0; r < 4; ++r) {
        s0 += silu_fast(acc0[r] + e0);
        s1 += silu_fast(acc1[r] + e1);
    }
    s0 += __shfl_xor(s0, 16); s0 += __shfl_xor(s0, 32);
    s1 += __shfl_xor(s1, 16); s1 += __shfl_xor(s1, 32);
    if (lg == 0) { lsPart[rt][cb][lr] = s0; lsPart[rt][cb + 1][lr] = s1; }
    __syncthreads();

    if (t < MM)
        mbuf[(size_t)i * MM + t] = lsPart[0][t >> 4][t & 15] + lsPart[1][t >> 4][t & 15];
}

// ---------------- deterministic column sum (stage 1) ------------------------
__global__ __launch_bounds__(256)
void colsum_kernel(const float* __restrict__ F, float* __restrict__ partial)
{
    __shared__ float ls[2][DD];
    const int b = blockIdx.x;
    const int t = threadIdx.x;
    const int c = t & 127, rg = t >> 7;
    float s = 0.0f;
    const int r0 = b * 64;
    for (int r = rg; r < 64; r += 2) s += F[(size_t)(r0 + r) * DD + c];
    ls[rg][c] = s;
    __syncthreads();
    if (t < DD) partial[(size_t)b * DD + t] = ls[0][t] + ls[1][t];
}

// ---------------- graph decoder + normalize (single block) ------------------
__global__ __launch_bounds__(128)
void final_kernel(const float* __restrict__ partial, const float* __restrict__ gw1,
                  const float* __restrict__ gb1, const float* __restrict__ gw2,
                  const float* __restrict__ gb2, float* __restrict__ out)
{
    __shared__ float lg[DD], lu[DD], red[DD];
    const int t = threadIdx.x;
    float s = 0.0f;
    for (int b = 0; b < 96; ++b) s += partial[(size_t)b * DD + t];
    lg[t] = s;
    __syncthreads();
    float a = 0.0f;
    for (int c = 0; c < DD; ++c) a += lg[c] * gw1[(size_t)c * DD + t];
    lu[t] = silu_f(a + gb1[t]);
    __syncthreads();
    float v = 0.0f;
    for (int c = 0; c < DD; ++c) v += lu[c] * gw2[(size_t)c * DD + t];
    v += gb2[t];
    red[t] = v * v;
    __syncthreads();
    for (int sft = 64; sft > 0; sft >>= 1) {
        if (t < sft) red[t] += red[t + sft];
        __syncthreads();
    }
    float nrm = sqrtf(red[0]);
    out[t] = v / fmaxf(nrm, 1e-12f);
}

// ---------------------------------------------------------------------------
extern "C" void kernel_launch(void* const* d_in, const int* in_sizes, int n_in,
                              void* d_out, int out_size, void* d_ws, size_t ws_size,
                              hipStream_t stream)
{
    const float* x      = (const float*)d_in[0];
    const float* coords = (const float*)d_in[1];
    const int*   ei     = (const int*)d_in[2];
    const float* w_enc  = (const float*)d_in[3];
    const float* b_enc  = (const float*)d_in[4];
    const float* ew1    = (const float*)d_in[5];
    const float* eb1    = (const float*)d_in[6];
    const float* ew2    = (const float*)d_in[7];
    const float* eb2    = (const float*)d_in[8];
    const float* nw1    = (const float*)d_in[9];
    const float* nb1    = (const float*)d_in[10];
    const float* nw2    = (const float*)d_in[11];
    const float* nb2    = (const float*)d_in[12];
    const float* dw1    = (const float*)d_in[13];
    const float* db1    = (const float*)d_in[14];
    const float* dw2    = (const float*)d_in[15];
    const float* db2    = (const float*)d_in[16];
    const float* gw1    = (const float*)d_in[17];
    const float* gb1    = (const float*)d_in[18];
    const float* gw2    = (const float*)d_in[19];
    const float* gb2    = (const float*)d_in[20];
    float* out = (float*)d_out;

    // workspace layout (float units)
    float* ws      = (float*)d_ws;
    float* feats   = ws;                          // 6144*128
    float* PQ      = feats + 786432;              // 6144*512 (decoder reuses as Fbuf)
    float* mbuf    = PQ + 3145728;                // 6144*64
    int*   idxbuf  = (int*)(mbuf + 393216);       // 6144*32
    float* rdbuf   = (float*)(idxbuf + 196608);   // 6144*32
    float* partial = rdbuf + 196608;              // 96*128
    unsigned short* w2p  = (unsigned short*)(partial + 12288);  // 6*16384
    unsigned short* Bpq  = w2p + 98304;           // 6*65536
    unsigned short* Bn1  = Bpq + 393216;          // 6*49152
    unsigned short* Bn2  = Bn1 + 294912;          // 6*32768
    unsigned short* Bd1  = Bn2 + 196608;          // 16384
    unsigned short* Bd2  = Bd1 + 16384;           // 16384
    unsigned short* Benc = Bd2 + 16384;           // 24*64*8 = 12288

    float* Fbuf = PQ;                  // decoder output (PQ dead by then)

    dim3 blk(256);

    neighbor_kernel<<<768, blk, 0, stream>>>(ei, coords, idxbuf, rdbuf);
    pack_all<<<502, blk, 0, stream>>>(ew1, ew2, nw1, nw2, dw1, dw2, w_enc,
                                      Bpq, Bn1, Bn2, w2p, Bd1, Bd2, Benc);
    // encoder (MFMA, K=68 padded to 96) -> feats
    mfma_gemm<96, 68, false, false, false><<<dim3(2, 96), blk, 0, stream>>>(
        x, Benc, b_enc, feats, 128);
    // layer-0 PQ (subsequent PQs are fused into node_mlp)
    mfma_gemm<128, 128, false, false, true><<<dim3(8, 96), blk, 0, stream>>>(
        feats, Bpq, eb1, PQ, 512);

    for (int l = 0; l < NL; ++l) {
        const float* W1 = ew1 + (size_t)l * 257 * 256;
        edge_kernel<<<NN, blk, 0, stream>>>(PQ, W1 + 256 * 256, w2p + (size_t)l * 16384,
                                            eb2 + l * 64, idxbuf, rdbuf, mbuf);
        if (l < NL - 1) {
            node_mlp<192, 256, true, true><<<192, blk, 0, stream>>>(
                feats, mbuf, Bn1 + (size_t)l * 49152, nb1 + l * 256,
                Bn2 + (size_t)l * 32768, nb2 + l * 128,
                Bpq + (size_t)(l + 1) * 65536, eb1 + (l + 1) * 256, feats, PQ);
        } else {
            node_mlp<192, 256, true, false><<<192, blk, 0, stream>>>(
                feats, mbuf, Bn1 + (size_t)l * 49152, nb1 + l * 256,
                Bn2 + (size_t)l * 32768, nb2 + l * 128,
                nullptr, nullptr, feats, nullptr);
        }
    }

    // node decoder (dw1+dw2 fused, no resid) -> Fbuf
    node_mlp<128, 128, false, false><<<192, blk, 0, stream>>>(
        feats, nullptr, Bd1, db1, Bd2, db2, nullptr, nullptr, Fbuf, nullptr);
    // graph sum + graph decoder + normalize
    colsum_kernel<<<96, blk, 0, stream>>>(Fbuf, partial);
    final_kernel<<<1, dim3(128), 0, stream>>>(partial, gw1, gb1, gw2, gb2, out);
}

// Round 13
// 442.053 us; speedup vs baseline: 4.6025x; 1.0513x over previous
//
#include <hip/hip_runtime.h>
#include <hip/hip_bf16.h>
#include <math.h>

// EGNN, N=6144, K=32, L=6, D=128, M=64, HE=256.
// Layer pipeline (2 dispatches/layer):
//   edge_kernel: hidden=silu(P+Q+rd*wr) -> MFMA [32,256]@[256,64] -> m  (per node)
//   node_mlp:    T=silu([feats|m]@nw1+nb1) -> feats=T@nw2+nb2+feats
//                -> PQ_next = feats@[ew1_fi|ew1_fj] (+eb1)   (fused, 16-row strips)
// All matmuls bf16-MFMA (16x16x32), weights pre-packed to B-fragment order.
// edge_kernel: launch_bounds(256,4) + explicit 16x B-frag register preload so
// Phase B is pure LDS+MFMA (round-12 counters showed VGPR=32 => serialized B loads).
// Neighbor selection = {self} + 31 lowest-index adj entries (order-invariant sum).

#define NN   6144
#define KNN  32
#define NL   6
#define DD   128
#define MM   64
#define HEE  256

typedef short bf16x8 __attribute__((ext_vector_type(8)));
typedef float f32x4  __attribute__((ext_vector_type(4)));

__device__ __forceinline__ float silu_f(float x) {
    return x / (1.0f + expf(-x));
}
__device__ __forceinline__ float silu_fast(float x) {
    return __fdividef(x, 1.0f + __expf(-x));
}
__device__ __forceinline__ unsigned short f2bf(float x) {
    __hip_bfloat16 b = __float2bfloat16(x);
    return *reinterpret_cast<unsigned short*>(&b);
}
__device__ __forceinline__ unsigned pack_bf2(float lo, float hi) {
    __hip_bfloat162 v = __float22bfloat162_rn(make_float2(lo, hi));
    return *reinterpret_cast<unsigned*>(&v);
}

// ---------------- bf16 MFMA GEMM (encoder + layer-0 PQ only) ----------------
template<int KN, int AW, bool SILU, bool RESID, bool PQB>
__global__ __launch_bounds__(256)
void mfma_gemm(const float* __restrict__ A, const unsigned short* __restrict__ Bp,
               const float* __restrict__ bias, float* __restrict__ C, int Nn)
{
    constexpr int NKS = KN / 32;
    constexpr int LDA = KN + 8;
    constexpr int C4  = KN / 4;
    __shared__ unsigned short lsA[64 * LDA];
    const int t = threadIdx.x;
    const int row0 = blockIdx.y * 64, col0 = blockIdx.x * 64;

#pragma unroll
    for (int u0 = 0; u0 < 64 * C4; u0 += 256) {
        int u = u0 + t;
        int r = u / C4, c4 = u % C4;
        float4 v = make_float4(0.f, 0.f, 0.f, 0.f);
        if (c4 * 4 < AW) v = *(const float4*)&A[(size_t)(row0 + r) * AW + c4 * 4];
        *(uint2*)&lsA[r * LDA + c4 * 4] = make_uint2(pack_bf2(v.x, v.y), pack_bf2(v.z, v.w));
    }
    __syncthreads();

    const int w = t >> 6, l = t & 63;
    const int wr = w & 1, wc = w >> 1;
    const int lr = l & 15, lg = l >> 4;
    const int ct0 = blockIdx.x * 4 + wc * 2;
    const int aoff = (wr * 32 + lr) * LDA + lg * 8;
    f32x4 acc[2][2] = {};
#pragma unroll
    for (int ks = 0; ks < NKS; ++ks) {
        bf16x8 a0 = *(const bf16x8*)&lsA[aoff + ks * 32];
        bf16x8 a1 = *(const bf16x8*)&lsA[aoff + 16 * LDA + ks * 32];
        bf16x8 b0 = *(const bf16x8*)&Bp[((size_t)(ct0 * NKS + ks) * 64 + l) * 8];
        bf16x8 b1 = *(const bf16x8*)&Bp[((size_t)((ct0 + 1) * NKS + ks) * 64 + l) * 8];
        acc[0][0] = __builtin_amdgcn_mfma_f32_16x16x32_bf16(a0, b0, acc[0][0], 0, 0, 0);
        acc[0][1] = __builtin_amdgcn_mfma_f32_16x16x32_bf16(a0, b1, acc[0][1], 0, 0, 0);
        acc[1][0] = __builtin_amdgcn_mfma_f32_16x16x32_bf16(a1, b0, acc[1][0], 0, 0, 0);
        acc[1][1] = __builtin_amdgcn_mfma_f32_16x16x32_bf16(a1, b1, acc[1][1], 0, 0, 0);
    }
#pragma unroll
    for (int rt = 0; rt < 2; ++rt) {
#pragma unroll
        for (int ctl = 0; ctl < 2; ++ctl) {
            int col = col0 + wc * 32 + ctl * 16 + lr;
            float bv = (!PQB || col < 256) ? bias[col] : 0.0f;
#pragma unroll
            for (int r = 0; r < 4; ++r) {
                int row = row0 + wr * 32 + rt * 16 + lg * 4 + r;
                float v = acc[rt][ctl][r] + bv;
                if (SILU) v = silu_f(v);
                size_t off = (size_t)row * Nn + col;
                if (RESID) v += C[off];
                C[off] = v;
            }
        }
    }
}

// ---------------- fused node MLP, 16-row strips (384 blocks) ----------------
// T = silu(A@B1+b1) [16,KH] in LDS; out = T@B2+b2 (+feats resid) -> outF;
// PQOUT: PQ = out@Bpq (+eb1 on cols<256) -> [16,512].
template<int KA, int KH, bool RESID, bool PQOUT>
__global__ __launch_bounds__(256, 4)
void node_mlp(const float* __restrict__ feats, const float* __restrict__ mbuf,
              const unsigned short* __restrict__ B1, const float* __restrict__ b1,
              const unsigned short* __restrict__ B2, const float* __restrict__ b2,
              const unsigned short* __restrict__ Bpq, const float* __restrict__ eb1,
              float* __restrict__ outF, float* __restrict__ PQ)
{
    constexpr int R   = 16;
    constexpr int LDA = KA + 8;
    constexpr int LDT = KH + 8;
    constexpr int KS1 = KA / 32;
    constexpr int KS2 = KH / 32;
    constexpr int CT1 = KH / 64;         // n1 col-tiles per wave
    constexpr int C4A = KA / 4;
    __shared__ unsigned short lsA[R * LDA];
    __shared__ unsigned short lsT[R * LDT];
    __shared__ unsigned short lsF[PQOUT ? R * 136 : 4];
    const int t = threadIdx.x;
    const int r0 = blockIdx.x * R;

    // stage A rows fp32->bf16 ([feats(128) | m(64)] for KA=192)
#pragma unroll
    for (int u0 = 0; u0 < R * C4A; u0 += 256) {
        int u = u0 + t;
        int r = u / C4A, c = (u % C4A) * 4;
        float4 v;
        if (KA == 128 || c < 128) v = *(const float4*)&feats[(size_t)(r0 + r) * DD + c];
        else                      v = *(const float4*)&mbuf[(size_t)(r0 + r) * MM + (c - 128)];
        *(uint2*)&lsA[r * LDA + c] = make_uint2(pack_bf2(v.x, v.y), pack_bf2(v.z, v.w));
    }
    __syncthreads();

    const int w = t >> 6, l = t & 63;
    const int lr = l & 15, lg = l >> 4;

    // ---- n1: T = silu(A@B1 + b1) ----
    {
        f32x4 acc[CT1] = {};
#pragma unroll
        for (int ks = 0; ks < KS1; ++ks) {
            bf16x8 a0 = *(const bf16x8*)&lsA[lr * LDA + ks * 32 + lg * 8];
#pragma unroll
            for (int ct = 0; ct < CT1; ++ct) {
                bf16x8 b = *(const bf16x8*)&B1[((size_t)((w * CT1 + ct) * KS1 + ks) * 64 + l) * 8];
                acc[ct] = __builtin_amdgcn_mfma_f32_16x16x32_bf16(a0, b, acc[ct], 0, 0, 0);
            }
        }
#pragma unroll
        for (int ct = 0; ct < CT1; ++ct) {
            int col = (w * CT1 + ct) * 16 + lr;
            float bv = b1[col];
#pragma unroll
            for (int r = 0; r < 4; ++r)
                lsT[(lg * 4 + r) * LDT + col] = f2bf(silu_f(acc[ct][r] + bv));
        }
    }
    __syncthreads();

    // ---- n2: out = T@B2 + b2 (+resid) ----
    {
        f32x4 acc[2] = {};
#pragma unroll
        for (int ks = 0; ks < KS2; ++ks) {
            bf16x8 a0 = *(const bf16x8*)&lsT[lr * LDT + ks * 32 + lg * 8];
#pragma unroll
            for (int ct = 0; ct < 2; ++ct) {
                bf16x8 b = *(const bf16x8*)&B2[((size_t)((w * 2 + ct) * KS2 + ks) * 64 + l) * 8];
                acc[ct] = __builtin_amdgcn_mfma_f32_16x16x32_bf16(a0, b, acc[ct], 0, 0, 0);
            }
        }
#pragma unroll
        for (int ct = 0; ct < 2; ++ct) {
            int col = (w * 2 + ct) * 16 + lr;
            float bv = b2[col];
#pragma unroll
            for (int r = 0; r < 4; ++r) {
                int row = lg * 4 + r;
                size_t off = (size_t)(r0 + row) * DD + col;
                float v = acc[ct][r] + bv;
                if (RESID) v += feats[off];
                outF[off] = v;
                if (PQOUT) lsF[row * 136 + col] = f2bf(v);
            }
        }
    }

    // ---- PQ for next layer: PQ = out@Bpq (+eb1 on P half) ----
    if (PQOUT) {
        __syncthreads();
        f32x4 acc[8] = {};
#pragma unroll
        for (int ks = 0; ks < 4; ++ks) {
            bf16x8 a0 = *(const bf16x8*)&lsF[lr * 136 + ks * 32 + lg * 8];
#pragma unroll
            for (int ct = 0; ct < 8; ++ct) {
                int ctg = w * 8 + ct;
                bf16x8 b = *(const bf16x8*)&Bpq[((size_t)(ctg * 4 + ks) * 64 + l) * 8];
                acc[ct] = __builtin_amdgcn_mfma_f32_16x16x32_bf16(a0, b, acc[ct], 0, 0, 0);
            }
        }
#pragma unroll
        for (int ct = 0; ct < 8; ++ct) {
            int col = (w * 8 + ct) * 16 + lr;
            float bv = (col < 256) ? eb1[col] : 0.0f;
#pragma unroll
            for (int r = 0; r < 4; ++r)
                PQ[(size_t)(r0 + lg * 4 + r) * 512 + col] = acc[ct][r] + bv;
        }
    }
}

// ---------------- unified weight pre-pack (unchanged layouts) ---------------
__global__ __launch_bounds__(256)
void pack_all(const float* __restrict__ ew1, const float* __restrict__ ew2,
              const float* __restrict__ nw1, const float* __restrict__ nw2,
              const float* __restrict__ dw1, const float* __restrict__ dw2,
              const float* __restrict__ wenc,
              unsigned short* __restrict__ Bpq, unsigned short* __restrict__ Bn1,
              unsigned short* __restrict__ Bn2, unsigned short* __restrict__ w2p,
              unsigned short* __restrict__ Bd1, unsigned short* __restrict__ Bd2,
              unsigned short* __restrict__ Benc)
{
    const int t = threadIdx.x;
    const int u = blockIdx.x * 4 + (t >> 6);
    if (u >= 2008) return;
    const int lane = t & 63;
    const float* src; unsigned short* dst;
    int nks, nc, ctd, ctc, ks, kmax = 1 << 30;
    if (u < 1920) {
        int l = u / 320, r = u % 320;
        if (r < 128) {                    // PQ: ew1 split-source, 32 ct x 4 ks
            ctd = r >> 2; ks = r & 3; nks = 4; nc = 256; ctc = ctd & 15;
            src = ew1 + (size_t)l * 257 * 256 + (ctd >= 16 ? 128 * 256 : 0);
            dst = Bpq + (size_t)l * 65536;
        } else if (r < 224) {             // n1: [192][256], 16 ct x 6 ks
            int rr = r - 128; ctd = rr / 6; ks = rr % 6; nks = 6; nc = 256; ctc = ctd;
            src = nw1 + (size_t)l * 192 * 256; dst = Bn1 + (size_t)l * 49152;
        } else if (r < 288) {             // n2: [256][128], 8 ct x 8 ks
            int rr = r - 224; ctd = rr >> 3; ks = rr & 7; nks = 8; nc = 128; ctc = ctd;
            src = nw2 + (size_t)l * 256 * 128; dst = Bn2 + (size_t)l * 32768;
        } else {                          // ew2: [256][64], 4 ct x 8 ks
            int rr = r - 288; ctd = rr >> 3; ks = rr & 7; nks = 8; nc = 64; ctc = ctd;
            src = ew2 + (size_t)l * 256 * 64; dst = w2p + (size_t)l * 16384;
        }
    } else if (u < 1984) {                // dw1/dw2: [128][128], 8 ct x 4 ks
        int rr = u - 1920;
        int m = rr >> 5; rr &= 31;
        ctd = rr >> 2; ks = rr & 3; nks = 4; nc = 128; ctc = ctd;
        src = m ? dw2 : dw1; dst = m ? Bd2 : Bd1;
    } else {                              // encoder: [68][128] pad K->96, 8 ct x 3 ks
        int rr = u - 1984;
        ctd = rr / 3; ks = rr % 3; nks = 3; nc = 128; ctc = ctd; kmax = 68;
        src = wenc; dst = Benc;
    }
    const int k0 = ks * 32 + (lane >> 4) * 8;
    const int col = ctc * 16 + (lane & 15);
    unsigned short* o = dst + ((size_t)(ctd * nks + ks) * 64 + lane) * 8;
#pragma unroll
    for (int j = 0; j < 8; ++j)
        o[j] = (k0 + j < kmax) ? f2bf(src[(size_t)(k0 + j) * nc + col]) : (unsigned short)0;
}

// ---------------- neighbor structure: thread = (node, k) edge slot ----------
__global__ __launch_bounds__(256)
void neighbor_kernel(const int* __restrict__ ei, const float* __restrict__ coords,
                     int* __restrict__ idx, float* __restrict__ rd)
{
    const int gid = blockIdx.x * 256 + threadIdx.x;
    const int i = gid >> 5, k = gid & 31;
    const int j = ei[(size_t)NN * KNN + (size_t)i * KNN + k];
    int dmax = j, kmax = k;
#pragma unroll
    for (int m = 1; m < 32; m <<= 1) {
        int od = __shfl_xor(dmax, m);
        int ok = __shfl_xor(kmax, m);
        if (od > dmax) { dmax = od; kmax = ok; }
    }
    int pos, jw;
    if (k == kmax) { pos = 0; jw = i; }
    else { pos = (k < kmax) ? k + 1 : k; jw = j; }
    float dx = coords[3 * i]     - coords[3 * jw];
    float dy = coords[3 * i + 1] - coords[3 * jw + 1];
    float dz = coords[3 * i + 2] - coords[3 * jw + 2];
    rd[(size_t)i * KNN + pos]  = dx * dx + dy * dy + dz * dz;
    idx[(size_t)i * KNN + pos] = jw;
}

// ---------------- fused edge kernel: one block per node, MFMA matvec --------
// Phase A: hidden = silu(P+Q+rd*wr) -> bf16 LDS (8 gathered rows in regs).
// B-frags preloaded into 16 registers before the barrier (launch_bounds(256,4)
// raises the VGPR cap so they stay resident). Phase B: pure LDS+MFMA.
__global__ __launch_bounds__(256, 4)
void edge_kernel(const float* __restrict__ PQ, const float* __restrict__ wr,
                 const unsigned short* __restrict__ w2p, const float* __restrict__ eb2,
                 const int* __restrict__ idx, const float* __restrict__ rd,
                 float* __restrict__ mbuf)
{
    __shared__ unsigned short lsH[32 * 264];
    __shared__ float lsPart[2][4][16];
    __shared__ int   lsIdx[KNN];
    __shared__ float lsRd[KNN];

    const int i = blockIdx.x;
    const int t = threadIdx.x;
    const int w = t >> 6, l = t & 63;
    const int rt = w & 1, cb = (w >> 1) * 2;
    const int lr = l & 15, lg = l >> 4;

    if (t < KNN) { lsIdx[t] = idx[(size_t)i * KNN + t]; lsRd[t] = rd[(size_t)i * KNN + t]; }
    __syncthreads();

    // Phase A
    {
        const int c0 = (t & 63) * 4;
        const int rg = t >> 6;
        float4 p4 = *(const float4*)&PQ[(size_t)i * 512 + c0];
        float4 w4 = *(const float4*)&wr[c0];
        int   jj[8]; float rr[8];
#pragma unroll
        for (int k = 0; k < 8; ++k) { jj[k] = lsIdx[rg * 8 + k]; rr[k] = lsRd[rg * 8 + k]; }
        float4 q[8];
#pragma unroll
        for (int k = 0; k < 8; ++k)
            q[k] = *(const float4*)&PQ[(size_t)jj[k] * 512 + 256 + c0];
        __builtin_amdgcn_sched_barrier(0);
#pragma unroll
        for (int k = 0; k < 8; ++k) {
            float a0 = silu_fast(fmaf(rr[k], w4.x, p4.x) + q[k].x);
            float a1 = silu_fast(fmaf(rr[k], w4.y, p4.y) + q[k].y);
            float a2 = silu_fast(fmaf(rr[k], w4.z, p4.z) + q[k].z);
            float a3 = silu_fast(fmaf(rr[k], w4.w, p4.w) + q[k].w);
            *(uint2*)&lsH[(rg * 8 + k) * 264 + c0] =
                make_uint2(pack_bf2(a0, a1), pack_bf2(a2, a3));
        }
    }

    // preload all 16 B fragments (L2-resident) so Phase B never touches global
    bf16x8 bfr[16];
#pragma unroll
    for (int ks = 0; ks < 8; ++ks) {
        bfr[2 * ks]     = *(const bf16x8*)&w2p[(size_t)(cb * 8 + ks) * 512 + l * 8];
        bfr[2 * ks + 1] = *(const bf16x8*)&w2p[(size_t)((cb + 1) * 8 + ks) * 512 + l * 8];
    }
    __syncthreads();

    // Phase B
    const int arow = rt * 16 + lr;
    f32x4 acc0 = {0.f, 0.f, 0.f, 0.f}, acc1 = {0.f, 0.f, 0.f, 0.f};
#pragma unroll
    for (int ks = 0; ks < 8; ++ks) {
        bf16x8 a = *(const bf16x8*)&lsH[arow * 264 + ks * 32 + lg * 8];
        acc0 = __builtin_amdgcn_mfma_f32_16x16x32_bf16(a, bfr[2 * ks],     acc0, 0, 0, 0);
        acc1 = __builtin_amdgcn_mfma_f32_16x16x32_bf16(a, bfr[2 * ks + 1], acc1, 0, 0, 0);
    }
    float e0 = eb2[cb * 16 + lr], e1 = eb2[(cb + 1) * 16 + lr];
    float s0 = 0.f, s1 = 0.f;
#pragma unroll
    for (int r = 0; r < 4; ++r) {
        s0 += silu_fast(acc0[r] + e0);
        s1 += silu_fast(acc1[r] + e1);
    }
    s0 += __shfl_xor(s0, 16); s0 += __shfl_xor(s0, 32);
    s1 += __shfl_xor(s1, 16); s1 += __shfl_xor(s1, 32);
    if (lg == 0) { lsPart[rt][cb][lr] = s0; lsPart[rt][cb + 1][lr] = s1; }
    __syncthreads();

    if (t < MM)
        mbuf[(size_t)i * MM + t] = lsPart[0][t >> 4][t & 15] + lsPart[1][t >> 4][t & 15];
}

// ---------------- deterministic column sum (stage 1) ------------------------
__global__ __launch_bounds__(256)
void colsum_kernel(const float* __restrict__ F, float* __restrict__ partial)
{
    __shared__ float ls[2][DD];
    const int b = blockIdx.x;
    const int t = threadIdx.x;
    const int c = t & 127, rg = t >> 7;
    float s = 0.0f;
    const int r0 = b * 64;
    for (int r = rg; r < 64; r += 2) s += F[(size_t)(r0 + r) * DD + c];
    ls[rg][c] = s;
    __syncthreads();
    if (t < DD) partial[(size_t)b * DD + t] = ls[0][t] + ls[1][t];
}

// ---------------- graph decoder + normalize (single block) ------------------
__global__ __launch_bounds__(128)
void final_kernel(const float* __restrict__ partial, const float* __restrict__ gw1,
                  const float* __restrict__ gb1, const float* __restrict__ gw2,
                  const float* __restrict__ gb2, float* __restrict__ out)
{
    __shared__ float lg[DD], lu[DD], red[DD];
    const int t = threadIdx.x;
    float s = 0.0f;
    for (int b = 0; b < 96; ++b) s += partial[(size_t)b * DD + t];
    lg[t] = s;
    __syncthreads();
    float a = 0.0f;
    for (int c = 0; c < DD; ++c) a += lg[c] * gw1[(size_t)c * DD + t];
    lu[t] = silu_f(a + gb1[t]);
    __syncthreads();
    float v = 0.0f;
    for (int c = 0; c < DD; ++c) v += lu[c] * gw2[(size_t)c * DD + t];
    v += gb2[t];
    red[t] = v * v;
    __syncthreads();
    for (int sft = 64; sft > 0; sft >>= 1) {
        if (t < sft) red[t] += red[t + sft];
        __syncthreads();
    }
    float nrm = sqrtf(red[0]);
    out[t] = v / fmaxf(nrm, 1e-12f);
}

// ---------------------------------------------------------------------------
extern "C" void kernel_launch(void* const* d_in, const int* in_sizes, int n_in,
                              void* d_out, int out_size, void* d_ws, size_t ws_size,
                              hipStream_t stream)
{
    const float* x      = (const float*)d_in[0];
    const float* coords = (const float*)d_in[1];
    const int*   ei     = (const int*)d_in[2];
    const float* w_enc  = (const float*)d_in[3];
    const float* b_enc  = (const float*)d_in[4];
    const float* ew1    = (const float*)d_in[5];
    const float* eb1    = (const float*)d_in[6];
    const float* ew2    = (const float*)d_in[7];
    const float* eb2    = (const float*)d_in[8];
    const float* nw1    = (const float*)d_in[9];
    const float* nb1    = (const float*)d_in[10];
    const float* nw2    = (const float*)d_in[11];
    const float* nb2    = (const float*)d_in[12];
    const float* dw1    = (const float*)d_in[13];
    const float* db1    = (const float*)d_in[14];
    const float* dw2    = (const float*)d_in[15];
    const float* db2    = (const float*)d_in[16];
    const float* gw1    = (const float*)d_in[17];
    const float* gb1    = (const float*)d_in[18];
    const float* gw2    = (const float*)d_in[19];
    const float* gb2    = (const float*)d_in[20];
    float* out = (float*)d_out;

    // workspace layout (float units)
    float* ws      = (float*)d_ws;
    float* feats   = ws;                          // 6144*128
    float* PQ      = feats + 786432;              // 6144*512 (decoder reuses as Fbuf)
    float* mbuf    = PQ + 3145728;                // 6144*64
    int*   idxbuf  = (int*)(mbuf + 393216);       // 6144*32
    float* rdbuf   = (float*)(idxbuf + 196608);   // 6144*32
    float* partial = rdbuf + 196608;              // 96*128
    unsigned short* w2p  = (unsigned short*)(partial + 12288);  // 6*16384
    unsigned short* Bpq  = w2p + 98304;           // 6*65536
    unsigned short* Bn1  = Bpq + 393216;          // 6*49152
    unsigned short* Bn2  = Bn1 + 294912;          // 6*32768
    unsigned short* Bd1  = Bn2 + 196608;          // 16384
    unsigned short* Bd2  = Bd1 + 16384;           // 16384
    unsigned short* Benc = Bd2 + 16384;           // 24*64*8 = 12288

    float* Fbuf = PQ;                  // decoder output (PQ dead by then)

    dim3 blk(256);

    neighbor_kernel<<<768, blk, 0, stream>>>(ei, coords, idxbuf, rdbuf);
    pack_all<<<502, blk, 0, stream>>>(ew1, ew2, nw1, nw2, dw1, dw2, w_enc,
                                      Bpq, Bn1, Bn2, w2p, Bd1, Bd2, Benc);
    // encoder (MFMA, K=68 padded to 96) -> feats
    mfma_gemm<96, 68, false, false, false><<<dim3(2, 96), blk, 0, stream>>>(
        x, Benc, b_enc, feats, 128);
    // layer-0 PQ (subsequent PQs fused into node_mlp)
    mfma_gemm<128, 128, false, false, true><<<dim3(8, 96), blk, 0, stream>>>(
        feats, Bpq, eb1, PQ, 512);

    for (int l = 0; l < NL; ++l) {
        edge_kernel<<<NN, blk, 0, stream>>>(PQ, ew1 + (size_t)l * 257 * 256 + 256 * 256,
                                            w2p + (size_t)l * 16384, eb2 + l * 64,
                                            idxbuf, rdbuf, mbuf);
        if (l < NL - 1) {
            node_mlp<192, 256, true, true><<<384, blk, 0, stream>>>(
                feats, mbuf, Bn1 + (size_t)l * 49152, nb1 + l * 256,
                Bn2 + (size_t)l * 32768, nb2 + l * 128,
                Bpq + (size_t)(l + 1) * 65536, eb1 + (l + 1) * 256, feats, PQ);
        } else {
            node_mlp<192, 256, true, false><<<384, blk, 0, stream>>>(
                feats, mbuf, Bn1 + (size_t)l * 49152, nb1 + l * 256,
                Bn2 + (size_t)l * 32768, nb2 + l * 128,
                nullptr, nullptr, feats, nullptr);
        }
    }

    // node decoder (dw1+dw2 fused, no resid) -> Fbuf
    node_mlp<128, 128, false, false><<<384, blk, 0, stream>>>(
        feats, nullptr, Bd1, db1, Bd2, db2, nullptr, nullptr, Fbuf, nullptr);
    // graph sum + graph decoder + normalize
    colsum_kernel<<<96, blk, 0, stream>>>(Fbuf, partial);
    final_kernel<<<1, dim3(128), 0, stream>>>(partial, gw1, gb1, gw2, gb2, out);
}